// Round 5
// baseline (289.553 us; speedup 1.0000x reference)
//
#include <hip/hip_runtime.h>

// TransformerBlock on MI355X: LN1 -> QKV -> causal MHA -> O-proj+res -> LN2 -> FFN+res
// R5: all GEMMs moved to 256x256-tile, BK=32, 8-wave, TRIPLE-buffered LDS with
// counted s_waitcnt vmcnt(4) + raw s_barrier (loads stay in flight 2 K-tiles ahead).
// Attention unchanged from R4 (KV-split + combine).

typedef __bf16 bf16_t;
typedef __attribute__((ext_vector_type(8))) __bf16 bf16x8;
typedef __attribute__((ext_vector_type(4))) __bf16 bf16x4;
typedef __attribute__((ext_vector_type(4))) float f32x4;

#define B_DIM 2
#define S_DIM 2048
#define E_DIM 1024
#define H_DIM 16
#define DH_DIM 64

#define GLD16(gp, lp) __builtin_amdgcn_global_load_lds( \
    (const __attribute__((address_space(1))) void*)(gp), \
    (__attribute__((address_space(3))) void*)(lp), 16, 0, 0)

// fold E^-0.5 (=1/32) and log2(e) into Q so softmax can use exp2 directly
#define Q_SCALE 0.0450842120f

// ---------------- LayerNorm: fp32 in -> bf16 out (one block per row) -------------
__global__ __launch_bounds__(256) void ln_kernel(
    const float* __restrict__ x, const float* __restrict__ g,
    const float* __restrict__ bv, bf16_t* __restrict__ out)
{
  const int row = blockIdx.x;
  const int t = threadIdx.x;
  const float* xr = x + (size_t)row * E_DIM;
  float4 v = *(const float4*)&xr[t * 4];
  float s  = v.x + v.y + v.z + v.w;
  float s2 = v.x*v.x + v.y*v.y + v.z*v.z + v.w*v.w;
#pragma unroll
  for (int m = 1; m < 64; m <<= 1) {
    s  += __shfl_xor(s,  m, 64);
    s2 += __shfl_xor(s2, m, 64);
  }
  __shared__ float red[8];
  const int wid = t >> 6, lane = t & 63;
  if (lane == 0) { red[wid] = s; red[4 + wid] = s2; }
  __syncthreads();
  s  = red[0] + red[1] + red[2] + red[3];
  s2 = red[4] + red[5] + red[6] + red[7];
  const float mu  = s * (1.f / E_DIM);
  const float var = s2 * (1.f / E_DIM) - mu * mu;
  const float rs  = rsqrtf(var + 1e-5f);
  float4 gg = *(const float4*)&g[t * 4];
  float4 bb = *(const float4*)&bv[t * 4];
  bf16x4 o;
  o[0] = (bf16_t)((v.x - mu) * rs * gg.x + bb.x);
  o[1] = (bf16_t)((v.y - mu) * rs * gg.y + bb.y);
  o[2] = (bf16_t)((v.z - mu) * rs * gg.z + bb.z);
  o[3] = (bf16_t)((v.w - mu) * rs * gg.w + bb.w);
  *(bf16x4*)&out[(size_t)row * E_DIM + t * 4] = o;
}

// ---- O-proj split-K combine + bias + residual -> xmid(f32), then LN2 -> h2(bf16) --
__global__ __launch_bounds__(256) void reduce2_ln(
    const float* __restrict__ p, const float* __restrict__ bo,
    const float* __restrict__ x, const float* __restrict__ g,
    const float* __restrict__ bv, float* __restrict__ xmid, bf16_t* __restrict__ h2)
{
  const int row = blockIdx.x;
  const int t = threadIdx.x;
  const size_t off = (size_t)row * E_DIM + t * 4;
  float4 a  = *(const float4*)&p[off];
  float4 b4 = *(const float4*)&p[(size_t)4096 * E_DIM + off];
  float4 xr = *(const float4*)&x[off];
  float4 bo4 = *(const float4*)&bo[t * 4];
  float4 v;
  v.x = a.x + b4.x + xr.x + bo4.x;
  v.y = a.y + b4.y + xr.y + bo4.y;
  v.z = a.z + b4.z + xr.z + bo4.z;
  v.w = a.w + b4.w + xr.w + bo4.w;
  *(float4*)&xmid[off] = v;
  float s  = v.x + v.y + v.z + v.w;
  float s2 = v.x*v.x + v.y*v.y + v.z*v.z + v.w*v.w;
#pragma unroll
  for (int m = 1; m < 64; m <<= 1) {
    s  += __shfl_xor(s,  m, 64);
    s2 += __shfl_xor(s2, m, 64);
  }
  __shared__ float red[8];
  const int wid = t >> 6, lane = t & 63;
  if (lane == 0) { red[wid] = s; red[4 + wid] = s2; }
  __syncthreads();
  s  = red[0] + red[1] + red[2] + red[3];
  s2 = red[4] + red[5] + red[6] + red[7];
  const float mu  = s * (1.f / E_DIM);
  const float var = s2 * (1.f / E_DIM) - mu * mu;
  const float rs  = rsqrtf(var + 1e-5f);
  float4 gg = *(const float4*)&g[t * 4];
  float4 bb = *(const float4*)&bv[t * 4];
  bf16x4 o;
  o[0] = (bf16_t)((v.x - mu) * rs * gg.x + bb.x);
  o[1] = (bf16_t)((v.y - mu) * rs * gg.y + bb.y);
  o[2] = (bf16_t)((v.z - mu) * rs * gg.z + bb.z);
  o[3] = (bf16_t)((v.w - mu) * rs * gg.w + bb.w);
  *(bf16x4*)&h2[off] = o;
}

// ---- FFN2 split-K combine (4 bf16 partials) + bias + residual -> d_out (f32) -----
__global__ __launch_bounds__(256) void reduce4(
    const bf16_t* __restrict__ p0, const bf16_t* __restrict__ p1,
    const bf16_t* __restrict__ p2, const bf16_t* __restrict__ p3,
    const float* __restrict__ b2, const float* __restrict__ xm,
    float* __restrict__ out)
{
  const int row = blockIdx.x;
  const int t = threadIdx.x;
  const size_t off = (size_t)row * E_DIM + t * 4;
  bf16x4 a0 = *(const bf16x4*)&p0[off];
  bf16x4 a1 = *(const bf16x4*)&p1[off];
  bf16x4 a2 = *(const bf16x4*)&p2[off];
  bf16x4 a3 = *(const bf16x4*)&p3[off];
  float4 xr = *(const float4*)&xm[off];
  float4 bb = *(const float4*)&b2[t * 4];
  float4 o;
  o.x = (float)a0[0] + (float)a1[0] + (float)a2[0] + (float)a3[0] + xr.x + bb.x;
  o.y = (float)a0[1] + (float)a1[1] + (float)a2[1] + (float)a3[1] + xr.y + bb.y;
  o.z = (float)a0[2] + (float)a1[2] + (float)a2[2] + (float)a3[2] + xr.z + bb.z;
  o.w = (float)a0[3] + (float)a1[3] + (float)a2[3] + (float)a3[3] + xr.w + bb.w;
  *(float4*)&out[off] = o;
}

// -------- generic transpose+cast: src [R][C] f32 -> dst [C][R] bf16 --------------
__global__ __launch_bounds__(256) void transpose_cast(
    const float* __restrict__ src, bf16_t* __restrict__ dst, int R, int C)
{
  __shared__ float tile[64][65];
  const int c0 = blockIdx.x * 64, r0 = blockIdx.y * 64;
  const int t = threadIdx.x;
  const int rr = t >> 2;
#pragma unroll
  for (int u = 0; u < 4; u++) {
    const int cc = (t & 3) * 4 + u * 16;
    float4 f = *(const float4*)&src[(size_t)(r0 + rr) * C + c0 + cc];
    tile[rr][cc + 0] = f.x; tile[rr][cc + 1] = f.y;
    tile[rr][cc + 2] = f.z; tile[rr][cc + 3] = f.w;
  }
  __syncthreads();
  const int oc = t >> 2;
#pragma unroll
  for (int u = 0; u < 4; u++) {
    const int orr = (t & 3) * 4 + u * 16;
    bf16x4 w;
    w[0] = (bf16_t)tile[orr + 0][oc];
    w[1] = (bf16_t)tile[orr + 1][oc];
    w[2] = (bf16_t)tile[orr + 2][oc];
    w[3] = (bf16_t)tile[orr + 3][oc];
    *(bf16x4*)&dst[(size_t)(c0 + oc) * R + r0 + orr] = w;
  }
}

// -------- QKV weight pack: W{q,k,v}[H][E][DH] f32 -> WqkvT[m*1024+h*64+d][e] bf16 --
__global__ __launch_bounds__(256) void qkv_transpose(
    const float* __restrict__ Wq, const float* __restrict__ Wk,
    const float* __restrict__ Wv, bf16_t* __restrict__ dstT)
{
  const int m = blockIdx.y >> 4, h = blockIdx.y & 15;
  const float* src = (m == 0 ? Wq : (m == 1 ? Wk : Wv)) + (size_t)h * E_DIM * DH_DIM;
  const int e0 = blockIdx.x * 64;
  __shared__ float tile[64][65];
  const int t = threadIdx.x;
  const int rr = t >> 2;
#pragma unroll
  for (int u = 0; u < 4; u++) {
    const int cc = (t & 3) * 4 + u * 16;
    float4 f = *(const float4*)&src[(size_t)(e0 + rr) * DH_DIM + cc];
    tile[rr][cc + 0] = f.x; tile[rr][cc + 1] = f.y;
    tile[rr][cc + 2] = f.z; tile[rr][cc + 3] = f.w;
  }
  __syncthreads();
  const int oc = t >> 2;  // d index 0..63
  const size_t drow = (size_t)(m * 1024 + h * 64 + oc) * E_DIM;
#pragma unroll
  for (int u = 0; u < 4; u++) {
    const int orr = (t & 3) * 4 + u * 16;
    bf16x4 w;
    w[0] = (bf16_t)tile[orr + 0][oc];
    w[1] = (bf16_t)tile[orr + 1][oc];
    w[2] = (bf16_t)tile[orr + 2][oc];
    w[3] = (bf16_t)tile[orr + 3][oc];
    *(bf16x4*)&dstT[drow + e0 + orr] = w;
  }
}

// ------------- 256x256-tile MFMA GEMM, BK=32, triple-buffered counted-vmcnt --------
// 512 threads = 8 waves (2 M x 4 N); per-wave output 128x64 = acc[8][4] f32x4.
// LDS: 3 bufs x (A 16KB + B 16KB) = 96 KB. Staging runs 2 K-tiles ahead; the wait is
// inline-asm vmcnt(4) + RAW s_barrier (no compiler vmcnt(0) drain). Race-free because
// stage(T+2) targets the buffer last read in body T-1, and the barrier at top of body
// T proves all waves finished T-1. LDS linear for global_load_lds; global source slot
// pre-XORed with (row&3); reads XOR the same -> conflict-free b128 column reads.
constexpr int EPI_QKV = 0, EPI_BIAS_RELU = 2, EPI_PART_F32 = 3, EPI_PART_B16 = 4;

template <int EPI>
__global__ __launch_bounds__(512, 2) void gemm256_kernel(
    const bf16_t* __restrict__ A, const bf16_t* __restrict__ Bt,
    int M, int N, int Kst, int Klen,
    const float* __restrict__ bias,
    float* __restrict__ outF, bf16_t* __restrict__ outB,
    bf16_t* __restrict__ qo, bf16_t* __restrict__ ko, bf16_t* __restrict__ vo)
{
  __shared__ bf16_t As[3][256 * 32];
  __shared__ bf16_t Bs[3][256 * 32];

  // bijective XCD swizzle within each z-slice (per-z nwg % 8 == 0 for all grids)
  const int gx = gridDim.x;
  const int nwg = gx * gridDim.y;
  int id = blockIdx.y * gx + blockIdx.x;
  id = (id & 7) * (nwg >> 3) + (id >> 3);
  const int m0 = (id % gx) * 256, n0 = (id / gx) * 256;
  const int sp = blockIdx.z;
  A  += (size_t)sp * Klen;
  Bt += (size_t)sp * Klen;

  const int tid = threadIdx.x, lane = tid & 63, wid = tid >> 6;
  const int wm = wid >> 2, wn = wid & 3;   // 2 x 4 wave grid
  const int lr = lane & 15, lg = lane >> 4;

  // per-thread staging coords: slot index s = p*512 + tid; row = s>>2, col-slot = s&3
  auto stage = [&](int kt, int buf) {
#pragma unroll
    for (int p = 0; p < 2; p++) {
      const int s = p * 512 + tid;
      const int r = s >> 2;
      const int sl = (s & 3) ^ (r & 3);
      const int ldsoff = (p * 512 + wid * 64) * 8;
      GLD16(A  + (size_t)(m0 + r) * Kst + kt * 32 + sl * 8, &As[buf][ldsoff]);
      GLD16(Bt + (size_t)(n0 + r) * Kst + kt * 32 + sl * 8, &Bs[buf][ldsoff]);
    }
  };

  const f32x4 z4 = {0.f, 0.f, 0.f, 0.f};
  f32x4 acc[8][4];
#pragma unroll
  for (int i = 0; i < 8; i++)
#pragma unroll
    for (int j = 0; j < 4; j++) acc[i][j] = z4;

  const int NT = Klen / 32;   // >= 16 for all our shapes
  stage(0, 0);
  stage(1, 1);
  for (int T = 0; T < NT; ++T) {
    const int b = T % 3;
    if (T + 2 < NT) {
      asm volatile("s_waitcnt vmcnt(4)" ::: "memory");  // tile T landed; T+1 in flight
      __builtin_amdgcn_s_barrier();                     // all waves: T ready, T-1 done
      stage(T + 2, (T + 2) % 3);                        // overwrites buf read in T-1
    } else if (T + 1 < NT) {
      asm volatile("s_waitcnt vmcnt(4)" ::: "memory");
      __builtin_amdgcn_s_barrier();
    } else {
      asm volatile("s_waitcnt vmcnt(0)" ::: "memory");
      __builtin_amdgcn_s_barrier();
    }
    __builtin_amdgcn_sched_barrier(0);  // no ds_read hoisting above the barrier

    bf16x8 bfr[4];
#pragma unroll
    for (int j = 0; j < 4; j++) {
      const int r = wn * 64 + j * 16 + lr;
      bfr[j] = *(const bf16x8*)&Bs[b][r * 32 + ((lg ^ (lr & 3)) * 8)];
    }
    __builtin_amdgcn_s_setprio(1);
#pragma unroll
    for (int i = 0; i < 8; i++) {
      const int r = wm * 128 + i * 16 + lr;
      bf16x8 af = *(const bf16x8*)&As[b][r * 32 + ((lg ^ (lr & 3)) * 8)];
#pragma unroll
      for (int j = 0; j < 4; j++)
        acc[i][j] = __builtin_amdgcn_mfma_f32_16x16x32_bf16(af, bfr[j], acc[i][j], 0, 0, 0);
    }
    __builtin_amdgcn_s_setprio(0);
  }

#pragma unroll
  for (int i = 0; i < 8; i++) {
#pragma unroll
    for (int j = 0; j < 4; j++) {
#pragma unroll
      for (int r = 0; r < 4; r++) {
        const int m = m0 + wm * 128 + i * 16 + lg * 4 + r;
        const int n = n0 + wn * 64 + j * 16 + lr;
        const float val = acc[i][j][r];
        if constexpr (EPI == EPI_QKV) {
          const int tsel = n >> 10, h = (n >> 6) & 15, d = n & 63;
          const int b_ = m >> 11, s_ = m & 2047;
          const size_t idx = ((size_t)((b_ * H_DIM + h) * S_DIM + s_)) * DH_DIM + d;
          if (tsel == 0)      qo[idx] = (bf16_t)(val * Q_SCALE);
          else if (tsel == 1) ko[idx] = (bf16_t)val;
          else                vo[idx] = (bf16_t)val;
        } else if constexpr (EPI == EPI_BIAS_RELU) {
          const float u = val + bias[n];
          outB[(size_t)m * N + n] = (bf16_t)(u > 0.f ? u : 0.f);
        } else if constexpr (EPI == EPI_PART_F32) {
          outF[(size_t)sp * M * N + (size_t)m * N + n] = val;
        } else {  // EPI_PART_B16
          bf16_t* o = sp == 0 ? outB : sp == 1 ? qo : sp == 2 ? ko : vo;
          o[(size_t)m * N + n] = (bf16_t)val;
        }
      }
    }
  }
}

// ---------------- causal flash attention, KV-split + double-buffered ---------------
__global__ __launch_bounds__(256) void attn_kernel(
    const bf16_t* __restrict__ Q, const bf16_t* __restrict__ K,
    const bf16_t* __restrict__ V, bf16_t* __restrict__ O,
    bf16_t* __restrict__ Opart, float* __restrict__ mpart, float* __restrict__ lpart)
{
  __shared__ bf16_t Ks[2][64 * 64];   // [t][d], swizzled: 16B slot ^= (t&7)
  __shared__ bf16_t Vst[2][64 * 64];  // [d][t], swizzled: slot ^= (d&7)^((d>>3)&7)
  __shared__ bf16_t Ps[4][16 * 64];   // per-wave [q][t], swizzled: slot ^= (q&7)

  const int nwg = 80 * gridDim.y;
  int id = blockIdx.y * 80 + blockIdx.x;
  id = (id & 7) * (nwg >> 3) + (id >> 3);
  const int bx = id % 80, bh = id / 80;

  int qt, sp, ns;
  if (bx < 8)       { qt = bx;                sp = 0;            ns = 1; }
  else if (bx < 24) { qt = 8 + ((bx - 8) >> 1);  sp = (bx - 8) & 1;  ns = 2; }
  else if (bx < 48) { const int u = bx - 24; const int q3 = u / 3;
                      qt = 16 + q3;           sp = u - q3 * 3;   ns = 3; }
  else              { const int u = bx - 48;  qt = 24 + (u >> 2); sp = u & 3; ns = 4; }
  const int n = qt + 1;
  const int lo = (sp * n) / ns, hi = ((sp + 1) * n) / ns;

  const int q0b = qt * 64;
  const int tid = threadIdx.x;
  const int wid = tid >> 6, lane = tid & 63;
  const int lr = lane & 15, lg = lane >> 4;
  const int q0w = q0b + wid * 16;

  const bf16_t* Qp = Q + (size_t)bh * S_DIM * DH_DIM;
  const bf16_t* Kp = K + (size_t)bh * S_DIM * DH_DIM;
  const bf16_t* Vp = V + (size_t)bh * S_DIM * DH_DIM;

  bf16x8 bq[2];
#pragma unroll
  for (int c = 0; c < 2; c++)
    bq[c] = *(const bf16x8*)&Qp[(size_t)(q0w + lr) * DH_DIM + c * 32 + lg * 8];

  const f32x4 z4 = {0.f, 0.f, 0.f, 0.f};
  f32x4 Ot[4];
#pragma unroll
  for (int dt = 0; dt < 4; dt++) Ot[dt] = z4;
  float mrow = -1e30f, lrow = 0.f;

  const int st = tid >> 3;        // staging row 0..31
  const int s8 = tid & 7;         // 16B slot in 128B row
  const int sbl = lane & 48;
  const int ktr = wid * 8 + (lane >> 3);
  const int ksc = (lane & 7);

  {
    const int t0 = lo * 64;
#pragma unroll
    for (int p = 0; p < 2; p++) {
      const int tr = p * 32 + ktr;
      GLD16(Kp + (size_t)(t0 + tr) * DH_DIM + (ksc ^ (tr & 7)) * 8,
            &Ks[0][(p * 32 + wid * 8) * 64]);
    }
  }
  bf16x8 vc0 = *(const bf16x8*)&Vp[(size_t)(lo * 64 + st) * DH_DIM + s8 * 8];
  bf16x8 vc1 = *(const bf16x8*)&Vp[(size_t)(lo * 64 + 32 + st) * DH_DIM + s8 * 8];
  bf16x8 vn0 = vc0, vn1 = vc1;

  for (int tc = lo; tc < hi; ++tc) {
    const int cur = (tc - lo) & 1;
#pragma unroll
    for (int h2 = 0; h2 < 2; h2++) {
      const bf16x8 vv = h2 ? vc1 : vc0;
      const int t = h2 * 32 + st;
#pragma unroll
      for (int j = 0; j < 8; j++) {
        const int d = s8 * 8 + j;
        const int f = j ^ s8;
        Vst[cur][(d * 128 + ((t * 2) ^ (f << 4))) >> 1] = vv[j];
      }
    }
    __syncthreads();
    if (tc + 1 < hi) {
      const int t1 = (tc + 1) * 64;
#pragma unroll
      for (int p = 0; p < 2; p++) {
        const int tr = p * 32 + ktr;
        GLD16(Kp + (size_t)(t1 + tr) * DH_DIM + (ksc ^ (tr & 7)) * 8,
              &Ks[cur ^ 1][(p * 32 + wid * 8) * 64]);
      }
      vn0 = *(const bf16x8*)&Vp[(size_t)(t1 + st) * DH_DIM + s8 * 8];
      vn1 = *(const bf16x8*)&Vp[(size_t)(t1 + 32 + st) * DH_DIM + s8 * 8];
    }

    const int t0 = tc * 64;
    f32x4 sc[4];
    __builtin_amdgcn_s_setprio(1);
#pragma unroll
    for (int j = 0; j < 4; j++) {
      f32x4 s = z4;
      const int t = j * 16 + lr;
#pragma unroll
      for (int c = 0; c < 2; c++) {
        const int kbyte = t * 128 + (((c * 4 + lg) * 16) ^ ((t & 7) << 4));
        bf16x8 ak = *(const bf16x8*)((const char*)&Ks[cur][0] + kbyte);
        s = __builtin_amdgcn_mfma_f32_16x16x32_bf16(ak, bq[c], s, 0, 0, 0);
      }
      sc[j] = s;
    }
    __builtin_amdgcn_s_setprio(0);
    if (tc == qt) {
#pragma unroll
      for (int j = 0; j < 4; j++)
#pragma unroll
        for (int r = 0; r < 4; r++) {
          const int tg = t0 + j * 16 + lg * 4 + r;
          if (tg > q0w + lr) sc[j][r] = -1e30f;
        }
    }
    float tmax = sc[0][0];
#pragma unroll
    for (int j = 0; j < 4; j++)
#pragma unroll
      for (int r = 0; r < 4; r++) tmax = fmaxf(tmax, sc[j][r]);
    tmax = fmaxf(tmax, __shfl_xor(tmax, 16, 64));
    tmax = fmaxf(tmax, __shfl_xor(tmax, 32, 64));
    const float mnew = fmaxf(mrow, tmax);
    const float fsc = __builtin_exp2f(mrow - mnew);
    mrow = mnew;
    float tsum = 0.f;
#pragma unroll
    for (int j = 0; j < 4; j++)
#pragma unroll
      for (int r = 0; r < 4; r++) {
        const float p = __builtin_exp2f(sc[j][r] - mnew);
        sc[j][r] = p;
        tsum += p;
      }
    tsum += __shfl_xor(tsum, 16, 64);
    tsum += __shfl_xor(tsum, 32, 64);
    lrow = lrow * fsc + tsum;

#pragma unroll
    for (int j = 0; j < 4; j++) {
      bf16x4 w;
#pragma unroll
      for (int r = 0; r < 4; r++) w[r] = (bf16_t)sc[j][r];
      const int pbyte = lr * 128 + ((j * 32 + lg * 8) ^ ((lr & 7) << 4));
      *(bf16x4*)((char*)&Ps[wid][0] + pbyte) = w;
    }
    float fr[4];
#pragma unroll
    for (int r = 0; r < 4; r++) fr[r] = __shfl(fsc, sbl | (lg * 4 + r), 64);
#pragma unroll
    for (int dt = 0; dt < 4; dt++)
#pragma unroll
      for (int r = 0; r < 4; r++) Ot[dt][r] *= fr[r];
    __builtin_amdgcn_s_setprio(1);
#pragma unroll
    for (int c = 0; c < 2; c++) {
      const int abyte = lr * 128 + ((c * 64 + lg * 16) ^ ((lr & 7) << 4));
      bf16x8 pa = *(const bf16x8*)((const char*)&Ps[wid][0] + abyte);
#pragma unroll
      for (int dt = 0; dt < 4; dt++) {
        const int d = dt * 16 + lr;
        const int f = (d & 7) ^ ((d >> 3) & 7);
        const int vbyte = d * 128 + (((c * 4 + lg) * 16) ^ (f << 4));
        bf16x8 bv = *(const bf16x8*)((const char*)&Vst[cur][0] + vbyte);
        Ot[dt] = __builtin_amdgcn_mfma_f32_16x16x32_bf16(pa, bv, Ot[dt], 0, 0, 0);
      }
    }
    __builtin_amdgcn_s_setprio(0);
    vc0 = vn0; vc1 = vn1;
  }

  if (ns == 1) {
    float linv[4];
#pragma unroll
    for (int r = 0; r < 4; r++)
      linv[r] = 1.f / __shfl(lrow, sbl | (lg * 4 + r), 64);
    const int b = bh >> 4, h = bh & 15;
#pragma unroll
    for (int r = 0; r < 4; r++) {
      const int s = q0w + lg * 4 + r;
      const size_t base = ((size_t)(b * S_DIM + s)) * E_DIM + h * DH_DIM;
#pragma unroll
      for (int dt = 0; dt < 4; dt++)
        O[base + dt * 16 + lr] = (bf16_t)(Ot[dt][r] * linv[r]);
    }
  } else {
    const int sbase = (qt < 16) ? 8 + 2 * (qt - 8)
                     : (qt < 24) ? 24 + 3 * (qt - 16) : 48 + 4 * (qt - 24);
    const int slot = bh * 80 + sbase + sp;
    bf16_t* Ob = Opart + (size_t)slot * 64 * 64;
#pragma unroll
    for (int r = 0; r < 4; r++)
#pragma unroll
      for (int dt = 0; dt < 4; dt++)
        Ob[(wid * 16 + lg * 4 + r) * 64 + dt * 16 + lr] = (bf16_t)Ot[dt][r];
    if (lg == 0) {
      mpart[slot * 64 + wid * 16 + lr] = mrow;
      lpart[slot * 64 + wid * 16 + lr] = lrow;
    }
  }
}

// ---------------- combine partials for qt >= 8 -------------------------------------
__global__ __launch_bounds__(256) void attn_combine(
    const bf16_t* __restrict__ Opart, const float* __restrict__ mpart,
    const float* __restrict__ lpart, bf16_t* __restrict__ O)
{
  const int qt = 8 + blockIdx.x;
  const int bh = blockIdx.y;
  const int ns = (qt < 16) ? 2 : (qt < 24) ? 3 : 4;
  const int sbase = (qt < 16) ? 8 + 2 * (qt - 8)
                   : (qt < 24) ? 24 + 3 * (qt - 16) : 48 + 4 * (qt - 24);
  const int slot0 = bh * 80 + sbase;
  const int tid = threadIdx.x;
  const int q = tid >> 2, d0 = (tid & 3) * 16;

  float M = -1e30f;
  for (int s = 0; s < ns; s++) M = fmaxf(M, mpart[(slot0 + s) * 64 + q]);
  float L = 0.f;
  float acc[16];
#pragma unroll
  for (int j = 0; j < 16; j++) acc[j] = 0.f;
  for (int s = 0; s < ns; s++) {
    const float w = __builtin_exp2f(mpart[(slot0 + s) * 64 + q] - M);
    L += w * lpart[(slot0 + s) * 64 + q];
    const bf16_t* Ob = Opart + ((size_t)(slot0 + s) * 64 + q) * 64 + d0;
    bf16x8 o0 = *(const bf16x8*)Ob;
    bf16x8 o1 = *(const bf16x8*)(Ob + 8);
#pragma unroll
    for (int j = 0; j < 8; j++) { acc[j] += w * (float)o0[j]; acc[8 + j] += w * (float)o1[j]; }
  }
  const float inv = 1.f / L;
  const int b = bh >> 4, h = bh & 15;
  const int srow = qt * 64 + q;
  bf16_t* out = O + ((size_t)(b * S_DIM + srow)) * E_DIM + h * DH_DIM + d0;
  bf16x8 w0, w1;
#pragma unroll
  for (int j = 0; j < 8; j++) { w0[j] = (bf16_t)(acc[j] * inv); w1[j] = (bf16_t)(acc[8 + j] * inv); }
  *(bf16x8*)out = w0;
  *(bf16x8*)(out + 8) = w1;
}

// ---------------- launcher ---------------------------------------------------------
extern "C" void kernel_launch(void* const* d_in, const int* in_sizes, int n_in,
                              void* d_out, int out_size, void* d_ws, size_t ws_size,
                              hipStream_t stream)
{
  const float* x    = (const float*)d_in[0];
  const float* ln1g = (const float*)d_in[1];
  const float* ln1b = (const float*)d_in[2];
  const float* Wq   = (const float*)d_in[3];
  const float* Wk   = (const float*)d_in[4];
  const float* Wv   = (const float*)d_in[5];
  const float* Wo   = (const float*)d_in[6];
  const float* bo   = (const float*)d_in[7];
  const float* ln2g = (const float*)d_in[8];
  const float* ln2b = (const float*)d_in[9];
  const float* W1   = (const float*)d_in[10];
  const float* b1   = (const float*)d_in[11];
  const float* W2   = (const float*)d_in[12];
  const float* b2   = (const float*)d_in[13];

  char* ws = (char*)d_ws;
  bf16_t* WqkvT = (bf16_t*)(ws + 0);          //  6.29 MB  [3072][1024] (dead after QKV)
  bf16_t* WoT   = (bf16_t*)(ws + 6291456);    //  2.10 MB  (dead after O-proj)
  bf16_t* W1T   = (bf16_t*)(ws + 8388608);    //  8.39 MB  (dead after FFN1)
  bf16_t* W2T   = (bf16_t*)(ws + 16777216);   //  8.39 MB
  bf16_t* h1    = (bf16_t*)(ws + 25165824);   //  8.39 MB  (dead after QKV)
  bf16_t* qb    = (bf16_t*)(ws + 33554432);   //  8.39 MB  (dead after attn)
  bf16_t* kb    = (bf16_t*)(ws + 41943040);   //  8.39 MB
  bf16_t* vb    = (bf16_t*)(ws + 50331648);   //  8.39 MB
  bf16_t* attnb = (bf16_t*)(ws + 58720256);   //  8.39 MB  (dead after O-proj)
  float*  xmid  = (float* )(ws + 67108864);   // 16.78 MB  f32
  bf16_t* h2    = (bf16_t*)(ws + 83886080);   //  8.39 MB  (dead after FFN1)
  bf16_t* ff1   = (bf16_t*)(ws + 25165824);   // 33.55 MB  over h1/qb/kb/vb (dead by FFN1)
  // attn partials: live attn->combine only; Opart overlaps xmid+h2 (written later)
  bf16_t* Opart = (bf16_t*)(ws + 67108864);   // 20.97 MB
  float*  mpart = (float* )(ws + 25165824);   //  0.66 MB (over h1, dead)
  float*  lpart = (float* )(ws + 25821184);   //  0.66 MB
  // O-proj split-K f32 partials [2][4096][1024]: over h1/qb/kb/vb (dead at O-proj)
  float*  po    = (float* )(ws + 25165824);   // 33.55 MB, consumed by reduce2_ln
  // FFN2 split-K bf16 partials [4096][1024] x4: over dead regions at FFN2 time
  bf16_t* pf0   = (bf16_t*)(ws + 0);          // over WqkvT+WoT
  bf16_t* pf1   = (bf16_t*)(ws + 8388608);    // over W1T
  bf16_t* pf2   = (bf16_t*)(ws + 58720256);   // over attnb
  bf16_t* pf3   = (bf16_t*)(ws + 83886080);   // over h2

  qkv_transpose<<<dim3(16, 48), 256, 0, stream>>>(Wq, Wk, Wv, WqkvT);
  transpose_cast<<<dim3(16, 16), 256, 0, stream>>>(Wo, WoT, 1024, 1024);
  transpose_cast<<<dim3(64, 16), 256, 0, stream>>>(W1, W1T, 1024, 4096);
  transpose_cast<<<dim3(16, 64), 256, 0, stream>>>(W2, W2T, 4096, 1024);

  ln_kernel<<<4096, 256, 0, stream>>>(x, ln1g, ln1b, h1);
  gemm256_kernel<EPI_QKV><<<dim3(16, 12, 1), 512, 0, stream>>>(
      h1, WqkvT, 4096, 3072, 1024, 1024, nullptr,
      nullptr, nullptr, qb, kb, vb);
  attn_kernel<<<dim3(80, 32), 256, 0, stream>>>(qb, kb, vb, attnb, Opart, mpart, lpart);
  attn_combine<<<dim3(24, 32), 256, 0, stream>>>(Opart, mpart, lpart, attnb);
  gemm256_kernel<EPI_PART_F32><<<dim3(16, 4, 2), 512, 0, stream>>>(
      attnb, WoT, 4096, 1024, 1024, 512, nullptr,
      po, nullptr, nullptr, nullptr, nullptr);
  reduce2_ln<<<4096, 256, 0, stream>>>(po, bo, x, ln2g, ln2b, xmid, h2);
  gemm256_kernel<EPI_BIAS_RELU><<<dim3(16, 16, 1), 512, 0, stream>>>(
      h2, W1T, 4096, 4096, 1024, 1024, b1,
      nullptr, ff1, nullptr, nullptr, nullptr);
  gemm256_kernel<EPI_PART_B16><<<dim3(16, 4, 4), 512, 0, stream>>>(
      ff1, W2T, 4096, 1024, 4096, 1024, nullptr,
      nullptr, pf0, pf1, pf2, pf3);
  reduce4<<<4096, 256, 0, stream>>>(pf0, pf1, pf2, pf3, b2, xmid, (float*)d_out);

  (void)in_sizes; (void)n_in; (void)out_size; (void)ws_size;
}

// Round 7
// 281.049 us; speedup vs baseline: 1.0303x; 1.0303x over previous
//
#include <hip/hip_runtime.h>

// TransformerBlock on MI355X: LN1 -> QKV -> causal MHA -> O-proj+res -> LN2 -> FFN+res
// R7: V stored TRANSPOSED ([b,h,d,s]) by the QKV epilogue, so attention stages V^T
// exactly like K (global_load_lds + row-XOR swizzle) and PV reads use the proven
// K-read pattern -- no VALU transpose, no tr-read. GEMMs: 128^2 (QKV/O-proj) and
// 256^2 (FFN) triple-buffered counted-vmcnt pipelines.

typedef __bf16 bf16_t;
typedef __attribute__((ext_vector_type(8))) __bf16 bf16x8;
typedef __attribute__((ext_vector_type(4))) __bf16 bf16x4;
typedef __attribute__((ext_vector_type(4))) float f32x4;

#define B_DIM 2
#define S_DIM 2048
#define E_DIM 1024
#define H_DIM 16
#define DH_DIM 64

#define GLD16(gp, lp) __builtin_amdgcn_global_load_lds( \
    (const __attribute__((address_space(1))) void*)(gp), \
    (__attribute__((address_space(3))) void*)(lp), 16, 0, 0)

// fold E^-0.5 (=1/32) and log2(e) into Q so softmax can use exp2 directly
#define Q_SCALE 0.0450842120f

// ---------------- LayerNorm: fp32 in -> bf16 out (one block per row) -------------
__global__ __launch_bounds__(256) void ln_kernel(
    const float* __restrict__ x, const float* __restrict__ g,
    const float* __restrict__ bv, bf16_t* __restrict__ out)
{
  const int row = blockIdx.x;
  const int t = threadIdx.x;
  const float* xr = x + (size_t)row * E_DIM;
  float4 v = *(const float4*)&xr[t * 4];
  float s  = v.x + v.y + v.z + v.w;
  float s2 = v.x*v.x + v.y*v.y + v.z*v.z + v.w*v.w;
#pragma unroll
  for (int m = 1; m < 64; m <<= 1) {
    s  += __shfl_xor(s,  m, 64);
    s2 += __shfl_xor(s2, m, 64);
  }
  __shared__ float red[8];
  const int wid = t >> 6, lane = t & 63;
  if (lane == 0) { red[wid] = s; red[4 + wid] = s2; }
  __syncthreads();
  s  = red[0] + red[1] + red[2] + red[3];
  s2 = red[4] + red[5] + red[6] + red[7];
  const float mu  = s * (1.f / E_DIM);
  const float var = s2 * (1.f / E_DIM) - mu * mu;
  const float rs  = rsqrtf(var + 1e-5f);
  float4 gg = *(const float4*)&g[t * 4];
  float4 bb = *(const float4*)&bv[t * 4];
  bf16x4 o;
  o[0] = (bf16_t)((v.x - mu) * rs * gg.x + bb.x);
  o[1] = (bf16_t)((v.y - mu) * rs * gg.y + bb.y);
  o[2] = (bf16_t)((v.z - mu) * rs * gg.z + bb.z);
  o[3] = (bf16_t)((v.w - mu) * rs * gg.w + bb.w);
  *(bf16x4*)&out[(size_t)row * E_DIM + t * 4] = o;
}

// ---- O-proj split-K combine + bias + residual -> xmid(f32), then LN2 -> h2(bf16) --
__global__ __launch_bounds__(256) void reduce2_ln(
    const float* __restrict__ p, const float* __restrict__ bo,
    const float* __restrict__ x, const float* __restrict__ g,
    const float* __restrict__ bv, float* __restrict__ xmid, bf16_t* __restrict__ h2)
{
  const int row = blockIdx.x;
  const int t = threadIdx.x;
  const size_t off = (size_t)row * E_DIM + t * 4;
  float4 a  = *(const float4*)&p[off];
  float4 b4 = *(const float4*)&p[(size_t)4096 * E_DIM + off];
  float4 xr = *(const float4*)&x[off];
  float4 bo4 = *(const float4*)&bo[t * 4];
  float4 v;
  v.x = a.x + b4.x + xr.x + bo4.x;
  v.y = a.y + b4.y + xr.y + bo4.y;
  v.z = a.z + b4.z + xr.z + bo4.z;
  v.w = a.w + b4.w + xr.w + bo4.w;
  *(float4*)&xmid[off] = v;
  float s  = v.x + v.y + v.z + v.w;
  float s2 = v.x*v.x + v.y*v.y + v.z*v.z + v.w*v.w;
#pragma unroll
  for (int m = 1; m < 64; m <<= 1) {
    s  += __shfl_xor(s,  m, 64);
    s2 += __shfl_xor(s2, m, 64);
  }
  __shared__ float red[8];
  const int wid = t >> 6, lane = t & 63;
  if (lane == 0) { red[wid] = s; red[4 + wid] = s2; }
  __syncthreads();
  s  = red[0] + red[1] + red[2] + red[3];
  s2 = red[4] + red[5] + red[6] + red[7];
  const float mu  = s * (1.f / E_DIM);
  const float var = s2 * (1.f / E_DIM) - mu * mu;
  const float rs  = rsqrtf(var + 1e-5f);
  float4 gg = *(const float4*)&g[t * 4];
  float4 bb = *(const float4*)&bv[t * 4];
  bf16x4 o;
  o[0] = (bf16_t)((v.x - mu) * rs * gg.x + bb.x);
  o[1] = (bf16_t)((v.y - mu) * rs * gg.y + bb.y);
  o[2] = (bf16_t)((v.z - mu) * rs * gg.z + bb.z);
  o[3] = (bf16_t)((v.w - mu) * rs * gg.w + bb.w);
  *(bf16x4*)&h2[off] = o;
}

// ---- FFN2 split-K combine (4 bf16 partials) + bias + residual -> d_out (f32) -----
__global__ __launch_bounds__(256) void reduce4(
    const bf16_t* __restrict__ p0, const bf16_t* __restrict__ p1,
    const bf16_t* __restrict__ p2, const bf16_t* __restrict__ p3,
    const float* __restrict__ b2, const float* __restrict__ xm,
    float* __restrict__ out)
{
  const int row = blockIdx.x;
  const int t = threadIdx.x;
  const size_t off = (size_t)row * E_DIM + t * 4;
  bf16x4 a0 = *(const bf16x4*)&p0[off];
  bf16x4 a1 = *(const bf16x4*)&p1[off];
  bf16x4 a2 = *(const bf16x4*)&p2[off];
  bf16x4 a3 = *(const bf16x4*)&p3[off];
  float4 xr = *(const float4*)&xm[off];
  float4 bb = *(const float4*)&b2[t * 4];
  float4 o;
  o.x = (float)a0[0] + (float)a1[0] + (float)a2[0] + (float)a3[0] + xr.x + bb.x;
  o.y = (float)a0[1] + (float)a1[1] + (float)a2[1] + (float)a3[1] + xr.y + bb.y;
  o.z = (float)a0[2] + (float)a1[2] + (float)a2[2] + (float)a3[2] + xr.z + bb.z;
  o.w = (float)a0[3] + (float)a1[3] + (float)a2[3] + (float)a3[3] + xr.w + bb.w;
  *(float4*)&out[off] = o;
}

// -------- generic transpose+cast: src [R][C] f32 -> dst [C][R] bf16 --------------
__global__ __launch_bounds__(256) void transpose_cast(
    const float* __restrict__ src, bf16_t* __restrict__ dst, int R, int C)
{
  __shared__ float tile[64][65];
  const int c0 = blockIdx.x * 64, r0 = blockIdx.y * 64;
  const int t = threadIdx.x;
  const int rr = t >> 2;
#pragma unroll
  for (int u = 0; u < 4; u++) {
    const int cc = (t & 3) * 4 + u * 16;
    float4 f = *(const float4*)&src[(size_t)(r0 + rr) * C + c0 + cc];
    tile[rr][cc + 0] = f.x; tile[rr][cc + 1] = f.y;
    tile[rr][cc + 2] = f.z; tile[rr][cc + 3] = f.w;
  }
  __syncthreads();
  const int oc = t >> 2;
#pragma unroll
  for (int u = 0; u < 4; u++) {
    const int orr = (t & 3) * 4 + u * 16;
    bf16x4 w;
    w[0] = (bf16_t)tile[orr + 0][oc];
    w[1] = (bf16_t)tile[orr + 1][oc];
    w[2] = (bf16_t)tile[orr + 2][oc];
    w[3] = (bf16_t)tile[orr + 3][oc];
    *(bf16x4*)&dst[(size_t)(c0 + oc) * R + r0 + orr] = w;
  }
}

// -------- QKV weight pack: W{q,k,v}[H][E][DH] f32 -> WqkvT[m*1024+h*64+d][e] bf16 --
__global__ __launch_bounds__(256) void qkv_transpose(
    const float* __restrict__ Wq, const float* __restrict__ Wk,
    const float* __restrict__ Wv, bf16_t* __restrict__ dstT)
{
  const int m = blockIdx.y >> 4, h = blockIdx.y & 15;
  const float* src = (m == 0 ? Wq : (m == 1 ? Wk : Wv)) + (size_t)h * E_DIM * DH_DIM;
  const int e0 = blockIdx.x * 64;
  __shared__ float tile[64][65];
  const int t = threadIdx.x;
  const int rr = t >> 2;
#pragma unroll
  for (int u = 0; u < 4; u++) {
    const int cc = (t & 3) * 4 + u * 16;
    float4 f = *(const float4*)&src[(size_t)(e0 + rr) * DH_DIM + cc];
    tile[rr][cc + 0] = f.x; tile[rr][cc + 1] = f.y;
    tile[rr][cc + 2] = f.z; tile[rr][cc + 3] = f.w;
  }
  __syncthreads();
  const int oc = t >> 2;  // d index 0..63
  const size_t drow = (size_t)(m * 1024 + h * 64 + oc) * E_DIM;
#pragma unroll
  for (int u = 0; u < 4; u++) {
    const int orr = (t & 3) * 4 + u * 16;
    bf16x4 w;
    w[0] = (bf16_t)tile[orr + 0][oc];
    w[1] = (bf16_t)tile[orr + 1][oc];
    w[2] = (bf16_t)tile[orr + 2][oc];
    w[3] = (bf16_t)tile[orr + 3][oc];
    *(bf16x4*)&dstT[drow + e0 + orr] = w;
  }
}

constexpr int EPI_QKV = 0, EPI_BIAS_RELU = 2, EPI_PART_F32 = 3, EPI_PART_B16 = 4;

// ------------- 128x128-tile MFMA GEMM, BK=32, triple-buffer counted-vmcnt ----------
// 256 threads = 4 waves (2x2); acc[4][4]. LDS 3 x (8K+8K) = 48 KB.
// NOTE (EPI_QKV): V output is written TRANSPOSED: vo[((b*16+h)*64+d)*2048+s].
template <int EPI>
__global__ __launch_bounds__(256) void gemm128_kernel(
    const bf16_t* __restrict__ A, const bf16_t* __restrict__ Bt,
    int M, int N, int Kst, int Klen,
    const float* __restrict__ bias,
    float* __restrict__ outF, bf16_t* __restrict__ outB,
    bf16_t* __restrict__ qo, bf16_t* __restrict__ ko, bf16_t* __restrict__ vo)
{
  __shared__ bf16_t As[3][128 * 32];
  __shared__ bf16_t Bs[3][128 * 32];
  const int gx = gridDim.x;
  const int nwg = gx * gridDim.y;
  int id = blockIdx.y * gx + blockIdx.x;
  id = (id & 7) * (nwg >> 3) + (id >> 3);
  const int m0 = (id % gx) * 128, n0 = (id / gx) * 128;
  const int sp = blockIdx.z;
  A  += (size_t)sp * Klen;
  Bt += (size_t)sp * Klen;

  const int tid = threadIdx.x, lane = tid & 63, wid = tid >> 6;
  const int wr = wid >> 1, wc = wid & 1;
  const int lr = lane & 15, lg = lane >> 4;

  auto stage = [&](int kt, int buf) {
#pragma unroll
    for (int p = 0; p < 2; p++) {
      const int s = p * 256 + tid;          // slot: row = s>>2, col-slot = s&3
      const int r = s >> 2;
      const int sl = (s & 3) ^ (r & 3);     // pre-swizzled global source
      const int lbase = (p * 256 + wid * 64) * 8;
      GLD16(A  + (size_t)(m0 + r) * Kst + kt * 32 + sl * 8, &As[buf][lbase]);
      GLD16(Bt + (size_t)(n0 + r) * Kst + kt * 32 + sl * 8, &Bs[buf][lbase]);
    }
  };

  const f32x4 z4 = {0.f, 0.f, 0.f, 0.f};
  f32x4 acc[4][4];
#pragma unroll
  for (int i = 0; i < 4; i++)
#pragma unroll
    for (int j = 0; j < 4; j++) acc[i][j] = z4;

  const int NT = Klen / 32;
  stage(0, 0);
  stage(1, 1);
  for (int T = 0; T < NT; ++T) {
    const int b = T % 3;
    if (T + 1 < NT) asm volatile("s_waitcnt vmcnt(4)" ::: "memory");
    else            asm volatile("s_waitcnt vmcnt(0)" ::: "memory");
    __builtin_amdgcn_s_barrier();
    if (T + 2 < NT) stage(T + 2, (T + 2) % 3);
    __builtin_amdgcn_sched_barrier(0);

    bf16x8 af[4], bfr[4];
#pragma unroll
    for (int j = 0; j < 4; j++) {
      const int r = wc * 64 + j * 16 + lr;
      bfr[j] = *(const bf16x8*)&Bs[b][r * 32 + ((lg ^ (lr & 3)) * 8)];
    }
#pragma unroll
    for (int i = 0; i < 4; i++) {
      const int r = wr * 64 + i * 16 + lr;
      af[i] = *(const bf16x8*)&As[b][r * 32 + ((lg ^ (lr & 3)) * 8)];
    }
    __builtin_amdgcn_s_setprio(1);
#pragma unroll
    for (int i = 0; i < 4; i++)
#pragma unroll
      for (int j = 0; j < 4; j++)
        acc[i][j] = __builtin_amdgcn_mfma_f32_16x16x32_bf16(af[i], bfr[j], acc[i][j], 0, 0, 0);
    __builtin_amdgcn_s_setprio(0);
  }

#pragma unroll
  for (int i = 0; i < 4; i++) {
#pragma unroll
    for (int j = 0; j < 4; j++) {
#pragma unroll
      for (int r = 0; r < 4; r++) {
        const int m = m0 + wr * 64 + i * 16 + lg * 4 + r;
        const int n = n0 + wc * 64 + j * 16 + lr;
        const float val = acc[i][j][r];
        if constexpr (EPI == EPI_QKV) {
          const int tsel = n >> 10, h = (n >> 6) & 15, d = n & 63;
          const int b_ = m >> 11, s_ = m & 2047;
          if (tsel == 0)
            qo[((size_t)((b_ * H_DIM + h) * S_DIM + s_)) * DH_DIM + d] = (bf16_t)(val * Q_SCALE);
          else if (tsel == 1)
            ko[((size_t)((b_ * H_DIM + h) * S_DIM + s_)) * DH_DIM + d] = (bf16_t)val;
          else  // V stored transposed: [b,h,d,s]
            vo[((size_t)((b_ * H_DIM + h) * DH_DIM + d)) * S_DIM + s_] = (bf16_t)val;
        } else if constexpr (EPI == EPI_BIAS_RELU) {
          const float u = val + bias[n];
          outB[(size_t)m * N + n] = (bf16_t)(u > 0.f ? u : 0.f);
        } else if constexpr (EPI == EPI_PART_F32) {
          outF[(size_t)sp * M * N + (size_t)m * N + n] = val;
        } else {
          bf16_t* o = sp == 0 ? outB : sp == 1 ? qo : sp == 2 ? ko : vo;
          o[(size_t)m * N + n] = (bf16_t)val;
        }
      }
    }
  }
}

// ------------- 256x256-tile MFMA GEMM, BK=32, triple-buffered counted-vmcnt --------
template <int EPI>
__global__ __launch_bounds__(512, 2) void gemm256_kernel(
    const bf16_t* __restrict__ A, const bf16_t* __restrict__ Bt,
    int M, int N, int Kst, int Klen,
    const float* __restrict__ bias,
    float* __restrict__ outF, bf16_t* __restrict__ outB,
    bf16_t* __restrict__ qo, bf16_t* __restrict__ ko, bf16_t* __restrict__ vo)
{
  __shared__ bf16_t As[3][256 * 32];
  __shared__ bf16_t Bs[3][256 * 32];
  const int gx = gridDim.x;
  const int nwg = gx * gridDim.y;
  int id = blockIdx.y * gx + blockIdx.x;
  id = (id & 7) * (nwg >> 3) + (id >> 3);
  const int m0 = (id % gx) * 256, n0 = (id / gx) * 256;
  const int sp = blockIdx.z;
  A  += (size_t)sp * Klen;
  Bt += (size_t)sp * Klen;

  const int tid = threadIdx.x, lane = tid & 63, wid = tid >> 6;
  const int wm = wid >> 2, wn = wid & 3;
  const int lr = lane & 15, lg = lane >> 4;

  auto stage = [&](int kt, int buf) {
#pragma unroll
    for (int p = 0; p < 2; p++) {
      const int s = p * 512 + tid;
      const int r = s >> 2;
      const int sl = (s & 3) ^ (r & 3);
      const int ldsoff = (p * 512 + wid * 64) * 8;
      GLD16(A  + (size_t)(m0 + r) * Kst + kt * 32 + sl * 8, &As[buf][ldsoff]);
      GLD16(Bt + (size_t)(n0 + r) * Kst + kt * 32 + sl * 8, &Bs[buf][ldsoff]);
    }
  };

  const f32x4 z4 = {0.f, 0.f, 0.f, 0.f};
  f32x4 acc[8][4];
#pragma unroll
  for (int i = 0; i < 8; i++)
#pragma unroll
    for (int j = 0; j < 4; j++) acc[i][j] = z4;

  const int NT = Klen / 32;
  stage(0, 0);
  stage(1, 1);
  for (int T = 0; T < NT; ++T) {
    const int b = T % 3;
    if (T + 1 < NT) asm volatile("s_waitcnt vmcnt(4)" ::: "memory");
    else            asm volatile("s_waitcnt vmcnt(0)" ::: "memory");
    __builtin_amdgcn_s_barrier();
    if (T + 2 < NT) stage(T + 2, (T + 2) % 3);
    __builtin_amdgcn_sched_barrier(0);

    bf16x8 bfr[4];
#pragma unroll
    for (int j = 0; j < 4; j++) {
      const int r = wn * 64 + j * 16 + lr;
      bfr[j] = *(const bf16x8*)&Bs[b][r * 32 + ((lg ^ (lr & 3)) * 8)];
    }
    __builtin_amdgcn_s_setprio(1);
#pragma unroll
    for (int i = 0; i < 8; i++) {
      const int r = wm * 128 + i * 16 + lr;
      bf16x8 af = *(const bf16x8*)&As[b][r * 32 + ((lg ^ (lr & 3)) * 8)];
#pragma unroll
      for (int j = 0; j < 4; j++)
        acc[i][j] = __builtin_amdgcn_mfma_f32_16x16x32_bf16(af, bfr[j], acc[i][j], 0, 0, 0);
    }
    __builtin_amdgcn_s_setprio(0);
  }

#pragma unroll
  for (int i = 0; i < 8; i++) {
#pragma unroll
    for (int j = 0; j < 4; j++) {
#pragma unroll
      for (int r = 0; r < 4; r++) {
        const int m = m0 + wm * 128 + i * 16 + lg * 4 + r;
        const int n = n0 + wn * 64 + j * 16 + lr;
        const float val = acc[i][j][r];
        if constexpr (EPI == EPI_BIAS_RELU) {
          const float u = val + bias[n];
          outB[(size_t)m * N + n] = (bf16_t)(u > 0.f ? u : 0.f);
        } else if constexpr (EPI == EPI_PART_F32) {
          outF[(size_t)sp * M * N + (size_t)m * N + n] = val;
        } else if constexpr (EPI == EPI_PART_B16) {
          bf16_t* o = sp == 0 ? outB : sp == 1 ? qo : sp == 2 ? ko : vo;
          o[(size_t)m * N + n] = (bf16_t)val;
        }
      }
    }
  }
}

// ---------------- causal flash attention, KV-split, V^T staging --------------------
// grid.x = 80 split-blocks per bh; block 256 = 4 waves; wave w owns q rows
// [qt*64+16w,+16). Swapped QK^T: lane lr holds q-row lr. K [t][d] and V^T [d][t]
// both staged by global_load_lds (double-buffered, row-XOR swizzle, 128B rows).
__global__ __launch_bounds__(256) void attn_kernel(
    const bf16_t* __restrict__ Q, const bf16_t* __restrict__ K,
    const bf16_t* __restrict__ Vt, bf16_t* __restrict__ O,
    bf16_t* __restrict__ Opart, float* __restrict__ mpart, float* __restrict__ lpart)
{
  __shared__ bf16_t Ks[2][64 * 64];   // [t][d], 16B slot ^= (t&7)
  __shared__ bf16_t Vs[2][64 * 64];   // [d][t], 16B slot ^= (d&7)
  __shared__ bf16_t Ps[4][16 * 64];   // per-wave [q][t], slot ^= (q&7)

  const int nwg = 80 * gridDim.y;
  int id = blockIdx.y * 80 + blockIdx.x;
  id = (id & 7) * (nwg >> 3) + (id >> 3);
  const int bx = id % 80, bh = id / 80;

  int qt, sp, ns;
  if (bx < 8)       { qt = bx;                sp = 0;            ns = 1; }
  else if (bx < 24) { qt = 8 + ((bx - 8) >> 1);  sp = (bx - 8) & 1;  ns = 2; }
  else if (bx < 48) { const int u = bx - 24; const int q3 = u / 3;
                      qt = 16 + q3;           sp = u - q3 * 3;   ns = 3; }
  else              { const int u = bx - 48;  qt = 24 + (u >> 2); sp = u & 3; ns = 4; }
  const int n = qt + 1;
  const int lo = (sp * n) / ns, hi = ((sp + 1) * n) / ns;

  const int q0b = qt * 64;
  const int tid = threadIdx.x;
  const int wid = tid >> 6, lane = tid & 63;
  const int lr = lane & 15, lg = lane >> 4;
  const int q0w = q0b + wid * 16;

  const bf16_t* Qp = Q  + (size_t)bh * S_DIM * DH_DIM;
  const bf16_t* Kp = K  + (size_t)bh * S_DIM * DH_DIM;
  const bf16_t* Vp = Vt + (size_t)bh * DH_DIM * S_DIM;  // [d][s]

  bf16x8 bq[2];
#pragma unroll
  for (int c = 0; c < 2; c++)
    bq[c] = *(const bf16x8*)&Qp[(size_t)(q0w + lr) * DH_DIM + c * 32 + lg * 8];

  const f32x4 z4 = {0.f, 0.f, 0.f, 0.f};
  f32x4 Ot[4];
#pragma unroll
  for (int dt = 0; dt < 4; dt++) Ot[dt] = z4;
  float mrow = -1e30f, lrow = 0.f;

  const int sbl = lane & 48;
  const int ktr = wid * 8 + (lane >> 3);  // row within 32-half
  const int ksc = lane & 7;               // 16B slot

  auto stageKV = [&](int t0, int buf) {
#pragma unroll
    for (int p = 0; p < 2; p++) {
      const int tr = p * 32 + ktr;   // K row (t) and V row (d), both in [0,64)
      GLD16(Kp + (size_t)(t0 + tr) * DH_DIM + (ksc ^ (tr & 7)) * 8,
            &Ks[buf][(p * 32 + wid * 8) * 64]);
      GLD16(Vp + (size_t)tr * S_DIM + t0 + (ksc ^ (tr & 7)) * 8,
            &Vs[buf][(p * 32 + wid * 8) * 64]);
    }
  };

  stageKV(lo * 64, 0);

  for (int tc = lo; tc < hi; ++tc) {
    const int cur = (tc - lo) & 1;
    __syncthreads();                       // drains stageKV(tc); prev buf free
    if (tc + 1 < hi) stageKV((tc + 1) * 64, cur ^ 1);  // flies under compute

    const int t0 = tc * 64;
    f32x4 sc[4];
    __builtin_amdgcn_s_setprio(1);
#pragma unroll
    for (int j = 0; j < 4; j++) {
      f32x4 s = z4;
      const int t = j * 16 + lr;
#pragma unroll
      for (int c = 0; c < 2; c++) {
        const int kbyte = t * 128 + (((c * 4 + lg) * 16) ^ ((t & 7) << 4));
        bf16x8 ak = *(const bf16x8*)((const char*)&Ks[cur][0] + kbyte);
        s = __builtin_amdgcn_mfma_f32_16x16x32_bf16(ak, bq[c], s, 0, 0, 0);
      }
      sc[j] = s;
    }
    __builtin_amdgcn_s_setprio(0);
    if (tc == qt) {
#pragma unroll
      for (int j = 0; j < 4; j++)
#pragma unroll
        for (int r = 0; r < 4; r++) {
          const int tg = t0 + j * 16 + lg * 4 + r;
          if (tg > q0w + lr) sc[j][r] = -1e30f;
        }
    }
    float tmax = sc[0][0];
#pragma unroll
    for (int j = 0; j < 4; j++)
#pragma unroll
      for (int r = 0; r < 4; r++) tmax = fmaxf(tmax, sc[j][r]);
    tmax = fmaxf(tmax, __shfl_xor(tmax, 16, 64));
    tmax = fmaxf(tmax, __shfl_xor(tmax, 32, 64));
    const float mnew = fmaxf(mrow, tmax);
    const float fsc = __builtin_exp2f(mrow - mnew);
    mrow = mnew;
    float tsum = 0.f;
#pragma unroll
    for (int j = 0; j < 4; j++)
#pragma unroll
      for (int r = 0; r < 4; r++) {
        const float p = __builtin_exp2f(sc[j][r] - mnew);
        sc[j][r] = p;
        tsum += p;
      }
    tsum += __shfl_xor(tsum, 16, 64);
    tsum += __shfl_xor(tsum, 32, 64);
    lrow = lrow * fsc + tsum;

#pragma unroll
    for (int j = 0; j < 4; j++) {
      bf16x4 w;
#pragma unroll
      for (int r = 0; r < 4; r++) w[r] = (bf16_t)sc[j][r];
      const int pbyte = lr * 128 + ((j * 32 + lg * 8) ^ ((lr & 7) << 4));
      *(bf16x4*)((char*)&Ps[wid][0] + pbyte) = w;
    }
    float fr[4];
#pragma unroll
    for (int r = 0; r < 4; r++) fr[r] = __shfl(fsc, sbl | (lg * 4 + r), 64);
#pragma unroll
    for (int dt = 0; dt < 4; dt++)
#pragma unroll
      for (int r = 0; r < 4; r++) Ot[dt][r] *= fr[r];

    // PV: A = P (LDS), B = V^T rows (same read pattern as K)
    __builtin_amdgcn_s_setprio(1);
#pragma unroll
    for (int c = 0; c < 2; c++) {
      const int abyte = lr * 128 + ((c * 64 + lg * 16) ^ ((lr & 7) << 4));
      bf16x8 pa = *(const bf16x8*)((const char*)&Ps[wid][0] + abyte);
#pragma unroll
      for (int dt = 0; dt < 4; dt++) {
        const int d = dt * 16 + lr;
        const int vbyte = d * 128 + (((c * 4 + lg) * 16) ^ ((d & 7) << 4));
        bf16x8 bv = *(const bf16x8*)((const char*)&Vs[cur][0] + vbyte);
        Ot[dt] = __builtin_amdgcn_mfma_f32_16x16x32_bf16(pa, bv, Ot[dt], 0, 0, 0);
      }
    }
    __builtin_amdgcn_s_setprio(0);
  }

  if (ns == 1) {
    float linv[4];
#pragma unroll
    for (int r = 0; r < 4; r++)
      linv[r] = 1.f / __shfl(lrow, sbl | (lg * 4 + r), 64);
    const int b = bh >> 4, h = bh & 15;
#pragma unroll
    for (int r = 0; r < 4; r++) {
      const int s = q0w + lg * 4 + r;
      const size_t base = ((size_t)(b * S_DIM + s)) * E_DIM + h * DH_DIM;
#pragma unroll
      for (int dt = 0; dt < 4; dt++)
        O[base + dt * 16 + lr] = (bf16_t)(Ot[dt][r] * linv[r]);
    }
  } else {
    const int sbase = (qt < 16) ? 8 + 2 * (qt - 8)
                     : (qt < 24) ? 24 + 3 * (qt - 16) : 48 + 4 * (qt - 24);
    const int slot = bh * 80 + sbase + sp;
    bf16_t* Ob = Opart + (size_t)slot * 64 * 64;
#pragma unroll
    for (int r = 0; r < 4; r++)
#pragma unroll
      for (int dt = 0; dt < 4; dt++)
        Ob[(wid * 16 + lg * 4 + r) * 64 + dt * 16 + lr] = (bf16_t)Ot[dt][r];
    if (lg == 0) {
      mpart[slot * 64 + wid * 16 + lr] = mrow;
      lpart[slot * 64 + wid * 16 + lr] = lrow;
    }
  }
}

// ---------------- combine partials for qt >= 8 -------------------------------------
__global__ __launch_bounds__(256) void attn_combine(
    const bf16_t* __restrict__ Opart, const float* __restrict__ mpart,
    const float* __restrict__ lpart, bf16_t* __restrict__ O)
{
  const int qt = 8 + blockIdx.x;
  const int bh = blockIdx.y;
  const int ns = (qt < 16) ? 2 : (qt < 24) ? 3 : 4;
  const int sbase = (qt < 16) ? 8 + 2 * (qt - 8)
                   : (qt < 24) ? 24 + 3 * (qt - 16) : 48 + 4 * (qt - 24);
  const int slot0 = bh * 80 + sbase;
  const int tid = threadIdx.x;
  const int q = tid >> 2, d0 = (tid & 3) * 16;

  float M = -1e30f;
  for (int s = 0; s < ns; s++) M = fmaxf(M, mpart[(slot0 + s) * 64 + q]);
  float L = 0.f;
  float acc[16];
#pragma unroll
  for (int j = 0; j < 16; j++) acc[j] = 0.f;
  for (int s = 0; s < ns; s++) {
    const float w = __builtin_exp2f(mpart[(slot0 + s) * 64 + q] - M);
    L += w * lpart[(slot0 + s) * 64 + q];
    const bf16_t* Ob = Opart + ((size_t)(slot0 + s) * 64 + q) * 64 + d0;
    bf16x8 o0 = *(const bf16x8*)Ob;
    bf16x8 o1 = *(const bf16x8*)(Ob + 8);
#pragma unroll
    for (int j = 0; j < 8; j++) { acc[j] += w * (float)o0[j]; acc[8 + j] += w * (float)o1[j]; }
  }
  const float inv = 1.f / L;
  const int b = bh >> 4, h = bh & 15;
  const int srow = qt * 64 + q;
  bf16_t* out = O + ((size_t)(b * S_DIM + srow)) * E_DIM + h * DH_DIM + d0;
  bf16x8 w0, w1;
#pragma unroll
  for (int j = 0; j < 8; j++) { w0[j] = (bf16_t)(acc[j] * inv); w1[j] = (bf16_t)(acc[8 + j] * inv); }
  *(bf16x8*)out = w0;
  *(bf16x8*)(out + 8) = w1;
}

// ---------------- launcher ---------------------------------------------------------
extern "C" void kernel_launch(void* const* d_in, const int* in_sizes, int n_in,
                              void* d_out, int out_size, void* d_ws, size_t ws_size,
                              hipStream_t stream)
{
  const float* x    = (const float*)d_in[0];
  const float* ln1g = (const float*)d_in[1];
  const float* ln1b = (const float*)d_in[2];
  const float* Wq   = (const float*)d_in[3];
  const float* Wk   = (const float*)d_in[4];
  const float* Wv   = (const float*)d_in[5];
  const float* Wo   = (const float*)d_in[6];
  const float* bo   = (const float*)d_in[7];
  const float* ln2g = (const float*)d_in[8];
  const float* ln2b = (const float*)d_in[9];
  const float* W1   = (const float*)d_in[10];
  const float* b1   = (const float*)d_in[11];
  const float* W2   = (const float*)d_in[12];
  const float* b2   = (const float*)d_in[13];

  char* ws = (char*)d_ws;
  bf16_t* WqkvT = (bf16_t*)(ws + 0);          //  6.29 MB (dead after QKV)
  bf16_t* WoT   = (bf16_t*)(ws + 6291456);    //  2.10 MB (dead after O-proj)
  bf16_t* W1T   = (bf16_t*)(ws + 8388608);    //  8.39 MB (dead after FFN1)
  bf16_t* W2T   = (bf16_t*)(ws + 16777216);   //  8.39 MB
  bf16_t* h1    = (bf16_t*)(ws + 25165824);   //  8.39 MB (dead after QKV)
  bf16_t* qb    = (bf16_t*)(ws + 33554432);   //  8.39 MB (dead after attn)
  bf16_t* kb    = (bf16_t*)(ws + 41943040);   //  8.39 MB
  bf16_t* vb    = (bf16_t*)(ws + 50331648);   //  8.39 MB  [b,h,d,s] transposed
  bf16_t* attnb = (bf16_t*)(ws + 58720256);   //  8.39 MB (dead after O-proj)
  float*  xmid  = (float* )(ws + 67108864);   // 16.78 MB f32
  bf16_t* h2    = (bf16_t*)(ws + 83886080);   //  8.39 MB (dead after FFN1)
  bf16_t* ff1   = (bf16_t*)(ws + 25165824);   // 33.55 MB over h1/qb/kb/vb
  bf16_t* Opart = (bf16_t*)(ws + 67108864);   // 20.97 MB (over xmid/h2, pre-O-proj only)
  float*  mpart = (float* )(ws + 25165824);   //  0.66 MB (over h1, dead)
  float*  lpart = (float* )(ws + 25821184);   //  0.66 MB
  float*  po    = (float* )(ws + 25165824);   // 33.55 MB O-proj f32 partials
  bf16_t* pf0   = (bf16_t*)(ws + 0);          // FFN2 partials over dead regions
  bf16_t* pf1   = (bf16_t*)(ws + 8388608);
  bf16_t* pf2   = (bf16_t*)(ws + 58720256);
  bf16_t* pf3   = (bf16_t*)(ws + 83886080);

  qkv_transpose<<<dim3(16, 48), 256, 0, stream>>>(Wq, Wk, Wv, WqkvT);
  transpose_cast<<<dim3(16, 16), 256, 0, stream>>>(Wo, WoT, 1024, 1024);
  transpose_cast<<<dim3(64, 16), 256, 0, stream>>>(W1, W1T, 1024, 4096);
  transpose_cast<<<dim3(16, 64), 256, 0, stream>>>(W2, W2T, 4096, 1024);

  ln_kernel<<<4096, 256, 0, stream>>>(x, ln1g, ln1b, h1);
  gemm128_kernel<EPI_QKV><<<dim3(32, 24, 1), 256, 0, stream>>>(
      h1, WqkvT, 4096, 3072, 1024, 1024, nullptr,
      nullptr, nullptr, qb, kb, vb);
  attn_kernel<<<dim3(80, 32), 256, 0, stream>>>(qb, kb, vb, attnb, Opart, mpart, lpart);
  attn_combine<<<dim3(24, 32), 256, 0, stream>>>(Opart, mpart, lpart, attnb);
  gemm128_kernel<EPI_PART_F32><<<dim3(32, 8, 2), 256, 0, stream>>>(
      attnb, WoT, 4096, 1024, 1024, 512, nullptr,
      po, nullptr, nullptr, nullptr, nullptr);
  reduce2_ln<<<4096, 256, 0, stream>>>(po, bo, x, ln2g, ln2b, xmid, h2);
  gemm256_kernel<EPI_BIAS_RELU><<<dim3(16, 16, 1), 512, 0, stream>>>(
      h2, W1T, 4096, 4096, 1024, 1024, b1,
      nullptr, ff1, nullptr, nullptr, nullptr);
  gemm256_kernel<EPI_PART_B16><<<dim3(16, 4, 4), 512, 0, stream>>>(
      ff1, W2T, 4096, 1024, 4096, 1024, nullptr,
      nullptr, pf0, pf1, pf2, pf3);
  reduce4<<<4096, 256, 0, stream>>>(pf0, pf1, pf2, pf3, b2, xmid, (float*)d_out);

  (void)in_sizes; (void)n_in; (void)out_size; (void)ws_size;
}

// Round 8
// 277.835 us; speedup vs baseline: 1.0422x; 1.0116x over previous
//
#include <hip/hip_runtime.h>

// TransformerBlock on MI355X: LN1 -> QKV -> causal MHA -> O-proj+res -> LN2 -> FFN+res
// R8: GEMM LDS moved to paired-row 128B layout with 3-bit XOR swizzle (conflict-free
// ds_read_b128; R7's 64B-row 2-bit swizzle left 4-way conflicts). Staging stays
// global_load_lds-linear via the inverse slot map. Everything else = R7.

typedef __bf16 bf16_t;
typedef __attribute__((ext_vector_type(8))) __bf16 bf16x8;
typedef __attribute__((ext_vector_type(4))) __bf16 bf16x4;
typedef __attribute__((ext_vector_type(4))) float f32x4;

#define B_DIM 2
#define S_DIM 2048
#define E_DIM 1024
#define H_DIM 16
#define DH_DIM 64

#define GLD16(gp, lp) __builtin_amdgcn_global_load_lds( \
    (const __attribute__((address_space(1))) void*)(gp), \
    (__attribute__((address_space(3))) void*)(lp), 16, 0, 0)

// fold E^-0.5 (=1/32) and log2(e) into Q so softmax can use exp2 directly
#define Q_SCALE 0.0450842120f

// ---------------- LayerNorm: fp32 in -> bf16 out (one block per row) -------------
__global__ __launch_bounds__(256) void ln_kernel(
    const float* __restrict__ x, const float* __restrict__ g,
    const float* __restrict__ bv, bf16_t* __restrict__ out)
{
  const int row = blockIdx.x;
  const int t = threadIdx.x;
  const float* xr = x + (size_t)row * E_DIM;
  float4 v = *(const float4*)&xr[t * 4];
  float s  = v.x + v.y + v.z + v.w;
  float s2 = v.x*v.x + v.y*v.y + v.z*v.z + v.w*v.w;
#pragma unroll
  for (int m = 1; m < 64; m <<= 1) {
    s  += __shfl_xor(s,  m, 64);
    s2 += __shfl_xor(s2, m, 64);
  }
  __shared__ float red[8];
  const int wid = t >> 6, lane = t & 63;
  if (lane == 0) { red[wid] = s; red[4 + wid] = s2; }
  __syncthreads();
  s  = red[0] + red[1] + red[2] + red[3];
  s2 = red[4] + red[5] + red[6] + red[7];
  const float mu  = s * (1.f / E_DIM);
  const float var = s2 * (1.f / E_DIM) - mu * mu;
  const float rs  = rsqrtf(var + 1e-5f);
  float4 gg = *(const float4*)&g[t * 4];
  float4 bb = *(const float4*)&bv[t * 4];
  bf16x4 o;
  o[0] = (bf16_t)((v.x - mu) * rs * gg.x + bb.x);
  o[1] = (bf16_t)((v.y - mu) * rs * gg.y + bb.y);
  o[2] = (bf16_t)((v.z - mu) * rs * gg.z + bb.z);
  o[3] = (bf16_t)((v.w - mu) * rs * gg.w + bb.w);
  *(bf16x4*)&out[(size_t)row * E_DIM + t * 4] = o;
}

// ---- O-proj split-K combine + bias + residual -> xmid(f32), then LN2 -> h2(bf16) --
__global__ __launch_bounds__(256) void reduce2_ln(
    const float* __restrict__ p, const float* __restrict__ bo,
    const float* __restrict__ x, const float* __restrict__ g,
    const float* __restrict__ bv, float* __restrict__ xmid, bf16_t* __restrict__ h2)
{
  const int row = blockIdx.x;
  const int t = threadIdx.x;
  const size_t off = (size_t)row * E_DIM + t * 4;
  float4 a  = *(const float4*)&p[off];
  float4 b4 = *(const float4*)&p[(size_t)4096 * E_DIM + off];
  float4 xr = *(const float4*)&x[off];
  float4 bo4 = *(const float4*)&bo[t * 4];
  float4 v;
  v.x = a.x + b4.x + xr.x + bo4.x;
  v.y = a.y + b4.y + xr.y + bo4.y;
  v.z = a.z + b4.z + xr.z + bo4.z;
  v.w = a.w + b4.w + xr.w + bo4.w;
  *(float4*)&xmid[off] = v;
  float s  = v.x + v.y + v.z + v.w;
  float s2 = v.x*v.x + v.y*v.y + v.z*v.z + v.w*v.w;
#pragma unroll
  for (int m = 1; m < 64; m <<= 1) {
    s  += __shfl_xor(s,  m, 64);
    s2 += __shfl_xor(s2, m, 64);
  }
  __shared__ float red[8];
  const int wid = t >> 6, lane = t & 63;
  if (lane == 0) { red[wid] = s; red[4 + wid] = s2; }
  __syncthreads();
  s  = red[0] + red[1] + red[2] + red[3];
  s2 = red[4] + red[5] + red[6] + red[7];
  const float mu  = s * (1.f / E_DIM);
  const float var = s2 * (1.f / E_DIM) - mu * mu;
  const float rs  = rsqrtf(var + 1e-5f);
  float4 gg = *(const float4*)&g[t * 4];
  float4 bb = *(const float4*)&bv[t * 4];
  bf16x4 o;
  o[0] = (bf16_t)((v.x - mu) * rs * gg.x + bb.x);
  o[1] = (bf16_t)((v.y - mu) * rs * gg.y + bb.y);
  o[2] = (bf16_t)((v.z - mu) * rs * gg.z + bb.z);
  o[3] = (bf16_t)((v.w - mu) * rs * gg.w + bb.w);
  *(bf16x4*)&h2[off] = o;
}

// ---- FFN2 split-K combine (4 bf16 partials) + bias + residual -> d_out (f32) -----
__global__ __launch_bounds__(256) void reduce4(
    const bf16_t* __restrict__ p0, const bf16_t* __restrict__ p1,
    const bf16_t* __restrict__ p2, const bf16_t* __restrict__ p3,
    const float* __restrict__ b2, const float* __restrict__ xm,
    float* __restrict__ out)
{
  const int row = blockIdx.x;
  const int t = threadIdx.x;
  const size_t off = (size_t)row * E_DIM + t * 4;
  bf16x4 a0 = *(const bf16x4*)&p0[off];
  bf16x4 a1 = *(const bf16x4*)&p1[off];
  bf16x4 a2 = *(const bf16x4*)&p2[off];
  bf16x4 a3 = *(const bf16x4*)&p3[off];
  float4 xr = *(const float4*)&xm[off];
  float4 bb = *(const float4*)&b2[t * 4];
  float4 o;
  o.x = (float)a0[0] + (float)a1[0] + (float)a2[0] + (float)a3[0] + xr.x + bb.x;
  o.y = (float)a0[1] + (float)a1[1] + (float)a2[1] + (float)a3[1] + xr.y + bb.y;
  o.z = (float)a0[2] + (float)a1[2] + (float)a2[2] + (float)a3[2] + xr.z + bb.z;
  o.w = (float)a0[3] + (float)a1[3] + (float)a2[3] + (float)a3[3] + xr.w + bb.w;
  *(float4*)&out[off] = o;
}

// -------- generic transpose+cast: src [R][C] f32 -> dst [C][R] bf16 --------------
__global__ __launch_bounds__(256) void transpose_cast(
    const float* __restrict__ src, bf16_t* __restrict__ dst, int R, int C)
{
  __shared__ float tile[64][65];
  const int c0 = blockIdx.x * 64, r0 = blockIdx.y * 64;
  const int t = threadIdx.x;
  const int rr = t >> 2;
#pragma unroll
  for (int u = 0; u < 4; u++) {
    const int cc = (t & 3) * 4 + u * 16;
    float4 f = *(const float4*)&src[(size_t)(r0 + rr) * C + c0 + cc];
    tile[rr][cc + 0] = f.x; tile[rr][cc + 1] = f.y;
    tile[rr][cc + 2] = f.z; tile[rr][cc + 3] = f.w;
  }
  __syncthreads();
  const int oc = t >> 2;
#pragma unroll
  for (int u = 0; u < 4; u++) {
    const int orr = (t & 3) * 4 + u * 16;
    bf16x4 w;
    w[0] = (bf16_t)tile[orr + 0][oc];
    w[1] = (bf16_t)tile[orr + 1][oc];
    w[2] = (bf16_t)tile[orr + 2][oc];
    w[3] = (bf16_t)tile[orr + 3][oc];
    *(bf16x4*)&dst[(size_t)(c0 + oc) * R + r0 + orr] = w;
  }
}

// -------- QKV weight pack: W{q,k,v}[H][E][DH] f32 -> WqkvT[m*1024+h*64+d][e] bf16 --
__global__ __launch_bounds__(256) void qkv_transpose(
    const float* __restrict__ Wq, const float* __restrict__ Wk,
    const float* __restrict__ Wv, bf16_t* __restrict__ dstT)
{
  const int m = blockIdx.y >> 4, h = blockIdx.y & 15;
  const float* src = (m == 0 ? Wq : (m == 1 ? Wk : Wv)) + (size_t)h * E_DIM * DH_DIM;
  const int e0 = blockIdx.x * 64;
  __shared__ float tile[64][65];
  const int t = threadIdx.x;
  const int rr = t >> 2;
#pragma unroll
  for (int u = 0; u < 4; u++) {
    const int cc = (t & 3) * 4 + u * 16;
    float4 f = *(const float4*)&src[(size_t)(e0 + rr) * DH_DIM + cc];
    tile[rr][cc + 0] = f.x; tile[rr][cc + 1] = f.y;
    tile[rr][cc + 2] = f.z; tile[rr][cc + 3] = f.w;
  }
  __syncthreads();
  const int oc = t >> 2;  // d index 0..63
  const size_t drow = (size_t)(m * 1024 + h * 64 + oc) * E_DIM;
#pragma unroll
  for (int u = 0; u < 4; u++) {
    const int orr = (t & 3) * 4 + u * 16;
    bf16x4 w;
    w[0] = (bf16_t)tile[orr + 0][oc];
    w[1] = (bf16_t)tile[orr + 1][oc];
    w[2] = (bf16_t)tile[orr + 2][oc];
    w[3] = (bf16_t)tile[orr + 3][oc];
    *(bf16x4*)&dstT[drow + e0 + orr] = w;
  }
}

constexpr int EPI_QKV = 0, EPI_BIAS_RELU = 2, EPI_PART_F32 = 3, EPI_PART_B16 = 4;

// LDS layout (both GEMMs): paired-row. Global (row r, 8-elem group u of 4) lives at
// LDS byte (r>>1)*128 + (((r&1)*4+u) ^ ((r>>1)&7))*16. 128B physical rows = full bank
// period; 3-bit XOR spreads the 8 slots; any 16-lane read quarter hits each slot 2x.
// Staging inverse: slot L -> row2=L>>3, s=(L&7)^(row2&7), r=row2*2+(s>>2), u=s&3.

// ------------- 128x128-tile MFMA GEMM, BK=32, triple-buffer counted-vmcnt ----------
template <int EPI>
__global__ __launch_bounds__(256) void gemm128_kernel(
    const bf16_t* __restrict__ A, const bf16_t* __restrict__ Bt,
    int M, int N, int Kst, int Klen,
    const float* __restrict__ bias,
    float* __restrict__ outF, bf16_t* __restrict__ outB,
    bf16_t* __restrict__ qo, bf16_t* __restrict__ ko, bf16_t* __restrict__ vo)
{
  __shared__ bf16_t As[3][128 * 32];
  __shared__ bf16_t Bs[3][128 * 32];
  const int gx = gridDim.x;
  const int nwg = gx * gridDim.y;
  int id = blockIdx.y * gx + blockIdx.x;
  id = (id & 7) * (nwg >> 3) + (id >> 3);
  const int m0 = (id % gx) * 128, n0 = (id / gx) * 128;
  const int sp = blockIdx.z;
  A  += (size_t)sp * Klen;
  Bt += (size_t)sp * Klen;

  const int tid = threadIdx.x, lane = tid & 63, wid = tid >> 6;
  const int wr = wid >> 1, wc = wid & 1;
  const int lr = lane & 15, lg = lane >> 4;
  const int halfr = lr >> 1;
  const int sl16 = (((lr & 1) * 4 + lg) ^ halfr) * 16;     // lane-constant byte slot
  const int baseA = (wr * 32 + halfr) * 128 + sl16;        // + i*1024
  const int baseB = (wc * 32 + halfr) * 128 + sl16;        // + j*1024

  auto stage = [&](int kt, int buf) {
#pragma unroll
    for (int p = 0; p < 2; p++) {
      const int L = p * 256 + tid;
      const int row2 = L >> 3;
      const int s = (L & 7) ^ (row2 & 7);
      const int r = row2 * 2 + (s >> 2);
      const int u = s & 3;
      char* lb = (char*)&As[buf][0] + (size_t)(p * 256 + wid * 64) * 16;
      char* lbB = (char*)&Bs[buf][0] + (size_t)(p * 256 + wid * 64) * 16;
      GLD16(A  + (size_t)(m0 + r) * Kst + kt * 32 + u * 8, lb);
      GLD16(Bt + (size_t)(n0 + r) * Kst + kt * 32 + u * 8, lbB);
    }
  };

  const f32x4 z4 = {0.f, 0.f, 0.f, 0.f};
  f32x4 acc[4][4];
#pragma unroll
  for (int i = 0; i < 4; i++)
#pragma unroll
    for (int j = 0; j < 4; j++) acc[i][j] = z4;

  const int NT = Klen / 32;
  stage(0, 0);
  stage(1, 1);
  for (int T = 0; T < NT; ++T) {
    const int b = T % 3;
    if (T + 1 < NT) asm volatile("s_waitcnt vmcnt(4)" ::: "memory");
    else            asm volatile("s_waitcnt vmcnt(0)" ::: "memory");
    __builtin_amdgcn_s_barrier();
    if (T + 2 < NT) stage(T + 2, (T + 2) % 3);
    __builtin_amdgcn_sched_barrier(0);

    bf16x8 af[4], bfr[4];
#pragma unroll
    for (int j = 0; j < 4; j++)
      bfr[j] = *(const bf16x8*)((const char*)&Bs[b][0] + baseB + j * 1024);
#pragma unroll
    for (int i = 0; i < 4; i++)
      af[i] = *(const bf16x8*)((const char*)&As[b][0] + baseA + i * 1024);
    __builtin_amdgcn_s_setprio(1);
#pragma unroll
    for (int i = 0; i < 4; i++)
#pragma unroll
      for (int j = 0; j < 4; j++)
        acc[i][j] = __builtin_amdgcn_mfma_f32_16x16x32_bf16(af[i], bfr[j], acc[i][j], 0, 0, 0);
    __builtin_amdgcn_s_setprio(0);
  }

#pragma unroll
  for (int i = 0; i < 4; i++) {
#pragma unroll
    for (int j = 0; j < 4; j++) {
#pragma unroll
      for (int r = 0; r < 4; r++) {
        const int m = m0 + wr * 64 + i * 16 + lg * 4 + r;
        const int n = n0 + wc * 64 + j * 16 + lr;
        const float val = acc[i][j][r];
        if constexpr (EPI == EPI_QKV) {
          const int tsel = n >> 10, h = (n >> 6) & 15, d = n & 63;
          const int b_ = m >> 11, s_ = m & 2047;
          if (tsel == 0)
            qo[((size_t)((b_ * H_DIM + h) * S_DIM + s_)) * DH_DIM + d] = (bf16_t)(val * Q_SCALE);
          else if (tsel == 1)
            ko[((size_t)((b_ * H_DIM + h) * S_DIM + s_)) * DH_DIM + d] = (bf16_t)val;
          else  // V stored transposed: [b,h,d,s]
            vo[((size_t)((b_ * H_DIM + h) * DH_DIM + d)) * S_DIM + s_] = (bf16_t)val;
        } else if constexpr (EPI == EPI_BIAS_RELU) {
          const float u = val + bias[n];
          outB[(size_t)m * N + n] = (bf16_t)(u > 0.f ? u : 0.f);
        } else if constexpr (EPI == EPI_PART_F32) {
          outF[(size_t)sp * M * N + (size_t)m * N + n] = val;
        } else {
          bf16_t* o = sp == 0 ? outB : sp == 1 ? qo : sp == 2 ? ko : vo;
          o[(size_t)m * N + n] = (bf16_t)val;
        }
      }
    }
  }
}

// ------------- 256x256-tile MFMA GEMM, BK=32, triple-buffered counted-vmcnt --------
template <int EPI>
__global__ __launch_bounds__(512, 2) void gemm256_kernel(
    const bf16_t* __restrict__ A, const bf16_t* __restrict__ Bt,
    int M, int N, int Kst, int Klen,
    const float* __restrict__ bias,
    float* __restrict__ outF, bf16_t* __restrict__ outB,
    bf16_t* __restrict__ qo, bf16_t* __restrict__ ko, bf16_t* __restrict__ vo)
{
  __shared__ bf16_t As[3][256 * 32];
  __shared__ bf16_t Bs[3][256 * 32];
  const int gx = gridDim.x;
  const int nwg = gx * gridDim.y;
  int id = blockIdx.y * gx + blockIdx.x;
  id = (id & 7) * (nwg >> 3) + (id >> 3);
  const int m0 = (id % gx) * 256, n0 = (id / gx) * 256;
  const int sp = blockIdx.z;
  A  += (size_t)sp * Klen;
  Bt += (size_t)sp * Klen;

  const int tid = threadIdx.x, lane = tid & 63, wid = tid >> 6;
  const int wm = wid >> 2, wn = wid & 3;
  const int lr = lane & 15, lg = lane >> 4;
  const int halfr = lr >> 1;
  const int sl16 = (((lr & 1) * 4 + lg) ^ halfr) * 16;
  const int baseA = (wm * 64 + halfr) * 128 + sl16;        // + i*1024
  const int baseB = (wn * 32 + halfr) * 128 + sl16;        // + j*1024

  auto stage = [&](int kt, int buf) {
#pragma unroll
    for (int p = 0; p < 2; p++) {
      const int L = p * 512 + tid;
      const int row2 = L >> 3;
      const int s = (L & 7) ^ (row2 & 7);
      const int r = row2 * 2 + (s >> 2);
      const int u = s & 3;
      char* lb = (char*)&As[buf][0] + (size_t)(p * 512 + wid * 64) * 16;
      char* lbB = (char*)&Bs[buf][0] + (size_t)(p * 512 + wid * 64) * 16;
      GLD16(A  + (size_t)(m0 + r) * Kst + kt * 32 + u * 8, lb);
      GLD16(Bt + (size_t)(n0 + r) * Kst + kt * 32 + u * 8, lbB);
    }
  };

  const f32x4 z4 = {0.f, 0.f, 0.f, 0.f};
  f32x4 acc[8][4];
#pragma unroll
  for (int i = 0; i < 8; i++)
#pragma unroll
    for (int j = 0; j < 4; j++) acc[i][j] = z4;

  const int NT = Klen / 32;
  stage(0, 0);
  stage(1, 1);
  for (int T = 0; T < NT; ++T) {
    const int b = T % 3;
    if (T + 1 < NT) asm volatile("s_waitcnt vmcnt(4)" ::: "memory");
    else            asm volatile("s_waitcnt vmcnt(0)" ::: "memory");
    __builtin_amdgcn_s_barrier();
    if (T + 2 < NT) stage(T + 2, (T + 2) % 3);
    __builtin_amdgcn_sched_barrier(0);

    bf16x8 bfr[4];
#pragma unroll
    for (int j = 0; j < 4; j++)
      bfr[j] = *(const bf16x8*)((const char*)&Bs[b][0] + baseB + j * 1024);
    __builtin_amdgcn_s_setprio(1);
#pragma unroll
    for (int i = 0; i < 8; i++) {
      bf16x8 af = *(const bf16x8*)((const char*)&As[b][0] + baseA + i * 1024);
#pragma unroll
      for (int j = 0; j < 4; j++)
        acc[i][j] = __builtin_amdgcn_mfma_f32_16x16x32_bf16(af, bfr[j], acc[i][j], 0, 0, 0);
    }
    __builtin_amdgcn_s_setprio(0);
  }

#pragma unroll
  for (int i = 0; i < 8; i++) {
#pragma unroll
    for (int j = 0; j < 4; j++) {
#pragma unroll
      for (int r = 0; r < 4; r++) {
        const int m = m0 + wm * 128 + i * 16 + lg * 4 + r;
        const int n = n0 + wn * 64 + j * 16 + lr;
        const float val = acc[i][j][r];
        if constexpr (EPI == EPI_BIAS_RELU) {
          const float u = val + bias[n];
          outB[(size_t)m * N + n] = (bf16_t)(u > 0.f ? u : 0.f);
        } else if constexpr (EPI == EPI_PART_F32) {
          outF[(size_t)sp * M * N + (size_t)m * N + n] = val;
        } else if constexpr (EPI == EPI_PART_B16) {
          bf16_t* o = sp == 0 ? outB : sp == 1 ? qo : sp == 2 ? ko : vo;
          o[(size_t)m * N + n] = (bf16_t)val;
        }
      }
    }
  }
}

// ---------------- causal flash attention, KV-split, V^T staging --------------------
__global__ __launch_bounds__(256) void attn_kernel(
    const bf16_t* __restrict__ Q, const bf16_t* __restrict__ K,
    const bf16_t* __restrict__ Vt, bf16_t* __restrict__ O,
    bf16_t* __restrict__ Opart, float* __restrict__ mpart, float* __restrict__ lpart)
{
  __shared__ bf16_t Ks[2][64 * 64];   // [t][d], 16B slot ^= (t&7)
  __shared__ bf16_t Vs[2][64 * 64];   // [d][t], 16B slot ^= (d&7)
  __shared__ bf16_t Ps[4][16 * 64];   // per-wave [q][t], slot ^= (q&7)

  const int nwg = 80 * gridDim.y;
  int id = blockIdx.y * 80 + blockIdx.x;
  id = (id & 7) * (nwg >> 3) + (id >> 3);
  const int bx = id % 80, bh = id / 80;

  int qt, sp, ns;
  if (bx < 8)       { qt = bx;                sp = 0;            ns = 1; }
  else if (bx < 24) { qt = 8 + ((bx - 8) >> 1);  sp = (bx - 8) & 1;  ns = 2; }
  else if (bx < 48) { const int u = bx - 24; const int q3 = u / 3;
                      qt = 16 + q3;           sp = u - q3 * 3;   ns = 3; }
  else              { const int u = bx - 48;  qt = 24 + (u >> 2); sp = u & 3; ns = 4; }
  const int n = qt + 1;
  const int lo = (sp * n) / ns, hi = ((sp + 1) * n) / ns;

  const int q0b = qt * 64;
  const int tid = threadIdx.x;
  const int wid = tid >> 6, lane = tid & 63;
  const int lr = lane & 15, lg = lane >> 4;
  const int q0w = q0b + wid * 16;

  const bf16_t* Qp = Q  + (size_t)bh * S_DIM * DH_DIM;
  const bf16_t* Kp = K  + (size_t)bh * S_DIM * DH_DIM;
  const bf16_t* Vp = Vt + (size_t)bh * DH_DIM * S_DIM;  // [d][s]

  bf16x8 bq[2];
#pragma unroll
  for (int c = 0; c < 2; c++)
    bq[c] = *(const bf16x8*)&Qp[(size_t)(q0w + lr) * DH_DIM + c * 32 + lg * 8];

  const f32x4 z4 = {0.f, 0.f, 0.f, 0.f};
  f32x4 Ot[4];
#pragma unroll
  for (int dt = 0; dt < 4; dt++) Ot[dt] = z4;
  float mrow = -1e30f, lrow = 0.f;

  const int sbl = lane & 48;
  const int ktr = wid * 8 + (lane >> 3);  // row within 32-half
  const int ksc = lane & 7;               // 16B slot

  auto stageKV = [&](int t0, int buf) {
#pragma unroll
    for (int p = 0; p < 2; p++) {
      const int tr = p * 32 + ktr;   // K row (t) and V row (d), both in [0,64)
      GLD16(Kp + (size_t)(t0 + tr) * DH_DIM + (ksc ^ (tr & 7)) * 8,
            &Ks[buf][(p * 32 + wid * 8) * 64]);
      GLD16(Vp + (size_t)tr * S_DIM + t0 + (ksc ^ (tr & 7)) * 8,
            &Vs[buf][(p * 32 + wid * 8) * 64]);
    }
  };

  stageKV(lo * 64, 0);

  for (int tc = lo; tc < hi; ++tc) {
    const int cur = (tc - lo) & 1;
    __syncthreads();                       // drains stageKV(tc); prev buf free
    if (tc + 1 < hi) stageKV((tc + 1) * 64, cur ^ 1);  // flies under compute

    const int t0 = tc * 64;
    f32x4 sc[4];
    __builtin_amdgcn_s_setprio(1);
#pragma unroll
    for (int j = 0; j < 4; j++) {
      f32x4 s = z4;
      const int t = j * 16 + lr;
#pragma unroll
      for (int c = 0; c < 2; c++) {
        const int kbyte = t * 128 + (((c * 4 + lg) * 16) ^ ((t & 7) << 4));
        bf16x8 ak = *(const bf16x8*)((const char*)&Ks[cur][0] + kbyte);
        s = __builtin_amdgcn_mfma_f32_16x16x32_bf16(ak, bq[c], s, 0, 0, 0);
      }
      sc[j] = s;
    }
    __builtin_amdgcn_s_setprio(0);
    if (tc == qt) {
#pragma unroll
      for (int j = 0; j < 4; j++)
#pragma unroll
        for (int r = 0; r < 4; r++) {
          const int tg = t0 + j * 16 + lg * 4 + r;
          if (tg > q0w + lr) sc[j][r] = -1e30f;
        }
    }
    float tmax = sc[0][0];
#pragma unroll
    for (int j = 0; j < 4; j++)
#pragma unroll
      for (int r = 0; r < 4; r++) tmax = fmaxf(tmax, sc[j][r]);
    tmax = fmaxf(tmax, __shfl_xor(tmax, 16, 64));
    tmax = fmaxf(tmax, __shfl_xor(tmax, 32, 64));
    const float mnew = fmaxf(mrow, tmax);
    const float fsc = __builtin_exp2f(mrow - mnew);
    mrow = mnew;
    float tsum = 0.f;
#pragma unroll
    for (int j = 0; j < 4; j++)
#pragma unroll
      for (int r = 0; r < 4; r++) {
        const float p = __builtin_exp2f(sc[j][r] - mnew);
        sc[j][r] = p;
        tsum += p;
      }
    tsum += __shfl_xor(tsum, 16, 64);
    tsum += __shfl_xor(tsum, 32, 64);
    lrow = lrow * fsc + tsum;

#pragma unroll
    for (int j = 0; j < 4; j++) {
      bf16x4 w;
#pragma unroll
      for (int r = 0; r < 4; r++) w[r] = (bf16_t)sc[j][r];
      const int pbyte = lr * 128 + ((j * 32 + lg * 8) ^ ((lr & 7) << 4));
      *(bf16x4*)((char*)&Ps[wid][0] + pbyte) = w;
    }
    float fr[4];
#pragma unroll
    for (int r = 0; r < 4; r++) fr[r] = __shfl(fsc, sbl | (lg * 4 + r), 64);
#pragma unroll
    for (int dt = 0; dt < 4; dt++)
#pragma unroll
      for (int r = 0; r < 4; r++) Ot[dt][r] *= fr[r];

    // PV: A = P (LDS), B = V^T rows (same read pattern as K)
    __builtin_amdgcn_s_setprio(1);
#pragma unroll
    for (int c = 0; c < 2; c++) {
      const int abyte = lr * 128 + ((c * 64 + lg * 16) ^ ((lr & 7) << 4));
      bf16x8 pa = *(const bf16x8*)((const char*)&Ps[wid][0] + abyte);
#pragma unroll
      for (int dt = 0; dt < 4; dt++) {
        const int d = dt * 16 + lr;
        const int vbyte = d * 128 + (((c * 4 + lg) * 16) ^ ((d & 7) << 4));
        bf16x8 bv = *(const bf16x8*)((const char*)&Vs[cur][0] + vbyte);
        Ot[dt] = __builtin_amdgcn_mfma_f32_16x16x32_bf16(pa, bv, Ot[dt], 0, 0, 0);
      }
    }
    __builtin_amdgcn_s_setprio(0);
  }

  if (ns == 1) {
    float linv[4];
#pragma unroll
    for (int r = 0; r < 4; r++)
      linv[r] = 1.f / __shfl(lrow, sbl | (lg * 4 + r), 64);
    const int b = bh >> 4, h = bh & 15;
#pragma unroll
    for (int r = 0; r < 4; r++) {
      const int s = q0w + lg * 4 + r;
      const size_t base = ((size_t)(b * S_DIM + s)) * E_DIM + h * DH_DIM;
#pragma unroll
      for (int dt = 0; dt < 4; dt++)
        O[base + dt * 16 + lr] = (bf16_t)(Ot[dt][r] * linv[r]);
    }
  } else {
    const int sbase = (qt < 16) ? 8 + 2 * (qt - 8)
                     : (qt < 24) ? 24 + 3 * (qt - 16) : 48 + 4 * (qt - 24);
    const int slot = bh * 80 + sbase + sp;
    bf16_t* Ob = Opart + (size_t)slot * 64 * 64;
#pragma unroll
    for (int r = 0; r < 4; r++)
#pragma unroll
      for (int dt = 0; dt < 4; dt++)
        Ob[(wid * 16 + lg * 4 + r) * 64 + dt * 16 + lr] = (bf16_t)Ot[dt][r];
    if (lg == 0) {
      mpart[slot * 64 + wid * 16 + lr] = mrow;
      lpart[slot * 64 + wid * 16 + lr] = lrow;
    }
  }
}

// ---------------- combine partials for qt >= 8 -------------------------------------
__global__ __launch_bounds__(256) void attn_combine(
    const bf16_t* __restrict__ Opart, const float* __restrict__ mpart,
    const float* __restrict__ lpart, bf16_t* __restrict__ O)
{
  const int qt = 8 + blockIdx.x;
  const int bh = blockIdx.y;
  const int ns = (qt < 16) ? 2 : (qt < 24) ? 3 : 4;
  const int sbase = (qt < 16) ? 8 + 2 * (qt - 8)
                   : (qt < 24) ? 24 + 3 * (qt - 16) : 48 + 4 * (qt - 24);
  const int slot0 = bh * 80 + sbase;
  const int tid = threadIdx.x;
  const int q = tid >> 2, d0 = (tid & 3) * 16;

  float M = -1e30f;
  for (int s = 0; s < ns; s++) M = fmaxf(M, mpart[(slot0 + s) * 64 + q]);
  float L = 0.f;
  float acc[16];
#pragma unroll
  for (int j = 0; j < 16; j++) acc[j] = 0.f;
  for (int s = 0; s < ns; s++) {
    const float w = __builtin_exp2f(mpart[(slot0 + s) * 64 + q] - M);
    L += w * lpart[(slot0 + s) * 64 + q];
    const bf16_t* Ob = Opart + ((size_t)(slot0 + s) * 64 + q) * 64 + d0;
    bf16x8 o0 = *(const bf16x8*)Ob;
    bf16x8 o1 = *(const bf16x8*)(Ob + 8);
#pragma unroll
    for (int j = 0; j < 8; j++) { acc[j] += w * (float)o0[j]; acc[8 + j] += w * (float)o1[j]; }
  }
  const float inv = 1.f / L;
  const int b = bh >> 4, h = bh & 15;
  const int srow = qt * 64 + q;
  bf16_t* out = O + ((size_t)(b * S_DIM + srow)) * E_DIM + h * DH_DIM + d0;
  bf16x8 w0, w1;
#pragma unroll
  for (int j = 0; j < 8; j++) { w0[j] = (bf16_t)(acc[j] * inv); w1[j] = (bf16_t)(acc[8 + j] * inv); }
  *(bf16x8*)out = w0;
  *(bf16x8*)(out + 8) = w1;
}

// ---------------- launcher ---------------------------------------------------------
extern "C" void kernel_launch(void* const* d_in, const int* in_sizes, int n_in,
                              void* d_out, int out_size, void* d_ws, size_t ws_size,
                              hipStream_t stream)
{
  const float* x    = (const float*)d_in[0];
  const float* ln1g = (const float*)d_in[1];
  const float* ln1b = (const float*)d_in[2];
  const float* Wq   = (const float*)d_in[3];
  const float* Wk   = (const float*)d_in[4];
  const float* Wv   = (const float*)d_in[5];
  const float* Wo   = (const float*)d_in[6];
  const float* bo   = (const float*)d_in[7];
  const float* ln2g = (const float*)d_in[8];
  const float* ln2b = (const float*)d_in[9];
  const float* W1   = (const float*)d_in[10];
  const float* b1   = (const float*)d_in[11];
  const float* W2   = (const float*)d_in[12];
  const float* b2   = (const float*)d_in[13];

  char* ws = (char*)d_ws;
  bf16_t* WqkvT = (bf16_t*)(ws + 0);          //  6.29 MB (dead after QKV)
  bf16_t* WoT   = (bf16_t*)(ws + 6291456);    //  2.10 MB (dead after O-proj)
  bf16_t* W1T   = (bf16_t*)(ws + 8388608);    //  8.39 MB (dead after FFN1)
  bf16_t* W2T   = (bf16_t*)(ws + 16777216);   //  8.39 MB
  bf16_t* h1    = (bf16_t*)(ws + 25165824);   //  8.39 MB (dead after QKV)
  bf16_t* qb    = (bf16_t*)(ws + 33554432);   //  8.39 MB (dead after attn)
  bf16_t* kb    = (bf16_t*)(ws + 41943040);   //  8.39 MB
  bf16_t* vb    = (bf16_t*)(ws + 50331648);   //  8.39 MB  [b,h,d,s] transposed
  bf16_t* attnb = (bf16_t*)(ws + 58720256);   //  8.39 MB (dead after O-proj)
  float*  xmid  = (float* )(ws + 67108864);   // 16.78 MB f32
  bf16_t* h2    = (bf16_t*)(ws + 83886080);   //  8.39 MB (dead after FFN1)
  bf16_t* ff1   = (bf16_t*)(ws + 25165824);   // 33.55 MB over h1/qb/kb/vb
  bf16_t* Opart = (bf16_t*)(ws + 67108864);   // 20.97 MB (over xmid/h2, pre-O-proj only)
  float*  mpart = (float* )(ws + 25165824);   //  0.66 MB (over h1, dead)
  float*  lpart = (float* )(ws + 25821184);   //  0.66 MB
  float*  po    = (float* )(ws + 25165824);   // 33.55 MB O-proj f32 partials
  bf16_t* pf0   = (bf16_t*)(ws + 0);          // FFN2 partials over dead regions
  bf16_t* pf1   = (bf16_t*)(ws + 8388608);
  bf16_t* pf2   = (bf16_t*)(ws + 58720256);
  bf16_t* pf3   = (bf16_t*)(ws + 83886080);

  qkv_transpose<<<dim3(16, 48), 256, 0, stream>>>(Wq, Wk, Wv, WqkvT);
  transpose_cast<<<dim3(16, 16), 256, 0, stream>>>(Wo, WoT, 1024, 1024);
  transpose_cast<<<dim3(64, 16), 256, 0, stream>>>(W1, W1T, 1024, 4096);
  transpose_cast<<<dim3(16, 64), 256, 0, stream>>>(W2, W2T, 4096, 1024);

  ln_kernel<<<4096, 256, 0, stream>>>(x, ln1g, ln1b, h1);
  gemm128_kernel<EPI_QKV><<<dim3(32, 24, 1), 256, 0, stream>>>(
      h1, WqkvT, 4096, 3072, 1024, 1024, nullptr,
      nullptr, nullptr, qb, kb, vb);
  attn_kernel<<<dim3(80, 32), 256, 0, stream>>>(qb, kb, vb, attnb, Opart, mpart, lpart);
  attn_combine<<<dim3(24, 32), 256, 0, stream>>>(Opart, mpart, lpart, attnb);
  gemm128_kernel<EPI_PART_F32><<<dim3(32, 8, 2), 256, 0, stream>>>(
      attnb, WoT, 4096, 1024, 1024, 512, nullptr,
      po, nullptr, nullptr, nullptr, nullptr);
  reduce2_ln<<<4096, 256, 0, stream>>>(po, bo, x, ln2g, ln2b, xmid, h2);
  gemm256_kernel<EPI_BIAS_RELU><<<dim3(16, 16, 1), 512, 0, stream>>>(
      h2, W1T, 4096, 4096, 1024, 1024, b1,
      nullptr, ff1, nullptr, nullptr, nullptr);
  gemm256_kernel<EPI_PART_B16><<<dim3(16, 4, 4), 512, 0, stream>>>(
      ff1, W2T, 4096, 1024, 4096, 1024, nullptr,
      nullptr, pf0, pf1, pf2, pf3);
  reduce4<<<4096, 256, 0, stream>>>(pf0, pf1, pf2, pf3, b2, xmid, (float*)d_out);

  (void)in_sizes; (void)n_in; (void)out_size; (void)ws_size;
}